// Round 1
// baseline (630.344 us; speedup 1.0000x reference)
//
#include <hip/hip_runtime.h>
#include <hip/hip_bf16.h>
#include <stdint.h>

#define B_ 2
#define H_ 8
#define N_ 2048
#define NS_ 2048
#define C_ 512
#define HD_ 64
#define SCALE_ 0.125f
#define NEG_ -10000.0f
#define LOG2E_ 1.4426950408889634f

typedef __bf16 bf16x8_t __attribute__((ext_vector_type(8)));
typedef float f32x4_t __attribute__((ext_vector_type(4)));

__device__ inline bf16x8_t load_bf8(const __hip_bfloat16* p) {
    union { uint4 u; bf16x8_t f; } cv;
    cv.u = *reinterpret_cast<const uint4*>(p);
    return cv.f;
}

// ---------------------------------------------------------------------------
// K1/K5: fp32 tiled GEMM  out[m,j] = sum_k A[m,k] * W[j,k]   (A @ W^T)
// mode 0/1: head-split fp32 + bf16 copy  (Q, K projections)
// mode 2:   transposed bf16 only [B,H,HD,NS] (V projection)
// mode 3:   flat fp32 (final output projection)
// ---------------------------------------------------------------------------
__global__ __launch_bounds__(256) void gemm512(const float* __restrict__ A,
        const float* __restrict__ W, float* __restrict__ outF,
        __hip_bfloat16* __restrict__ outB, int mode)
{
    __shared__ float As[16][68];
    __shared__ float Bs[16][68];
    const int t  = threadIdx.x;
    const int tx = t & 15, ty = t >> 4;
    const int bm = blockIdx.x << 6, bn = blockIdx.y << 6;
    const int lr = t >> 2, lk = (t & 3) << 2;
    const float* Ap = A + (size_t)(bm + lr) * C_ + lk;
    const float* Wp = W + (size_t)(bn + lr) * C_ + lk;
    float acc[4][4] = {};
    for (int k0 = 0; k0 < C_; k0 += 16) {
        float4 av = *reinterpret_cast<const float4*>(Ap + k0);
        float4 wv = *reinterpret_cast<const float4*>(Wp + k0);
        __syncthreads();
        As[lk+0][lr]=av.x; As[lk+1][lr]=av.y; As[lk+2][lr]=av.z; As[lk+3][lr]=av.w;
        Bs[lk+0][lr]=wv.x; Bs[lk+1][lr]=wv.y; Bs[lk+2][lr]=wv.z; Bs[lk+3][lr]=wv.w;
        __syncthreads();
        #pragma unroll
        for (int kk = 0; kk < 16; kk++) {
            float4 a = *reinterpret_cast<const float4*>(&As[kk][ty<<2]);
            float4 b = *reinterpret_cast<const float4*>(&Bs[kk][tx<<2]);
            acc[0][0] += a.x*b.x; acc[0][1] += a.x*b.y; acc[0][2] += a.x*b.z; acc[0][3] += a.x*b.w;
            acc[1][0] += a.y*b.x; acc[1][1] += a.y*b.y; acc[1][2] += a.y*b.z; acc[1][3] += a.y*b.w;
            acc[2][0] += a.z*b.x; acc[2][1] += a.z*b.y; acc[2][2] += a.z*b.z; acc[2][3] += a.z*b.w;
            acc[3][0] += a.w*b.x; acc[3][1] += a.w*b.y; acc[3][2] += a.w*b.z; acc[3][3] += a.w*b.w;
        }
    }
    #pragma unroll
    for (int i = 0; i < 4; i++) {
        const int gm = bm + (ty<<2) + i;
        const int b = gm >> 11, n = gm & 2047;
        #pragma unroll
        for (int j = 0; j < 4; j++) {
            const int gj = bn + (tx<<2) + j;
            const float val = acc[i][j];
            if (mode == 3) {
                outF[(size_t)gm * C_ + gj] = val;
            } else if (mode == 2) {
                const int h = gj >> 6, d = gj & 63;
                outB[(((size_t)(b*H_ + h)*HD_ + d) << 11) + n] = __float2bfloat16(val);
            } else {
                const int h = gj >> 6, d = gj & 63;
                const size_t idx = ((((size_t)(b*H_ + h)) << 11) + n) * HD_ + d;
                outF[idx] = val;
                outB[idx] = __float2bfloat16(val);
            }
        }
    }
}

// ---------------------------------------------------------------------------
// K2: fp32 row-argmax of A @ B^T over 64-dim dots.
// Run twice: (qh,kh)->q2k and (kh,qh)->k2q. Packed atomicMax reproduces
// first-index tie-break: (ordered_float << 32) | ~idx.
// ---------------------------------------------------------------------------
__device__ inline unsigned long long packArg(float v, int idx) {
    unsigned u = __float_as_uint(v);
    u = (u & 0x80000000u) ? ~u : (u | 0x80000000u);
    return ((unsigned long long)u << 32) | (unsigned)(~idx);
}

__global__ __launch_bounds__(256) void argmax_pass(const float* __restrict__ Af,
        const float* __restrict__ Bf, unsigned long long* __restrict__ outP)
{
    const int bh = blockIdx.x, rt = blockIdx.y, ct = blockIdx.z;
    const int t = threadIdx.x, w = t >> 6, lane = t & 63;
    const int r0 = (rt << 9) + (w << 7) + lane;
    const int r1 = r0 + 64;
    const float* Abh = Af + (((size_t)bh) << 11) * HD_;
    const float* Bbh = Bf + (((size_t)bh) << 11) * HD_;
    float q0[64], q1[64];
    #pragma unroll
    for (int i = 0; i < 16; i++) {
        float4 v0 = *reinterpret_cast<const float4*>(Abh + (size_t)r0*HD_ + (i<<2));
        float4 v1 = *reinterpret_cast<const float4*>(Abh + (size_t)r1*HD_ + (i<<2));
        q0[(i<<2)+0]=v0.x; q0[(i<<2)+1]=v0.y; q0[(i<<2)+2]=v0.z; q0[(i<<2)+3]=v0.w;
        q1[(i<<2)+0]=v1.x; q1[(i<<2)+1]=v1.y; q1[(i<<2)+2]=v1.z; q1[(i<<2)+3]=v1.w;
    }
    __shared__ float Bs[64][68];
    float best0 = -3.4e38f, best1 = -3.4e38f;
    int bi0 = 0, bi1 = 0;
    for (int cc = 0; cc < 256; cc += 64) {
        const int cbase = (ct << 8) + cc;
        __syncthreads();
        {
            const int col = t >> 2, seg = t & 3;
            const float* src = Bbh + (size_t)(cbase + col)*HD_ + (seg<<4);
            const int dbase = seg << 4;
            #pragma unroll
            for (int j = 0; j < 4; j++) {
                float4 u = reinterpret_cast<const float4*>(src)[j];
                Bs[col][dbase + (j<<2) + 0] = u.x;
                Bs[col][dbase + (j<<2) + 1] = u.y;
                Bs[col][dbase + (j<<2) + 2] = u.z;
                Bs[col][dbase + (j<<2) + 3] = u.w;
            }
        }
        __syncthreads();
        for (int c = 0; c < 64; c++) {
            float a0 = 0.f, a1 = 0.f;
            #pragma unroll
            for (int d = 0; d < 64; d += 4) {
                float4 bv = *reinterpret_cast<const float4*>(&Bs[c][d]);
                a0 += q0[d+0]*bv.x; a0 += q0[d+1]*bv.y; a0 += q0[d+2]*bv.z; a0 += q0[d+3]*bv.w;
                a1 += q1[d+0]*bv.x; a1 += q1[d+1]*bv.y; a1 += q1[d+2]*bv.z; a1 += q1[d+3]*bv.w;
            }
            const int gc = cbase + c;
            if (a0 > best0) { best0 = a0; bi0 = gc; }
            if (a1 > best1) { best1 = a1; bi1 = gc; }
        }
    }
    atomicMax(outP + ((size_t)bh << 11) + r0, packArg(best0, bi0));
    atomicMax(outP + ((size_t)bh << 11) + r1, packArg(best1, bi1));
}

// ---------------------------------------------------------------------------
// K3: cycle-consistency resolve -> validNeg[b,h,j] = valid * NEG
// ---------------------------------------------------------------------------
__global__ __launch_bounds__(256) void resolve(const unsigned long long* __restrict__ q2kP,
        const unsigned long long* __restrict__ k2qP, const int* __restrict__ supp_mask,
        const float* __restrict__ supp_valid, float* __restrict__ validNeg)
{
    const int t = blockIdx.x * 256 + threadIdx.x;      // 32768 = B*H*NS
    const int bh = t >> 11, j = t & 2047, b = bh >> 3;
    const unsigned k2q = 0xFFFFFFFFu - (unsigned)(k2qP[t] & 0xFFFFFFFFull);
    const unsigned rm  = 0xFFFFFFFFu - (unsigned)(q2kP[(bh << 11) + k2q] & 0xFFFFFFFFull);
    const int asso = supp_mask[(b << 11) + j] == supp_mask[(b << 11) + (int)rm];
    const float valid = asso ? supp_valid[(b << 11) + j] : 1.0f;
    validNeg[t] = valid * NEG_;
}

// ---------------------------------------------------------------------------
// K4a: masked softmax stats (rowmax m, rowsum l) via bf16 MFMA, exp2 domain.
// One wave = 16 query rows x all 2048 keys.
// ---------------------------------------------------------------------------
__global__ __launch_bounds__(256) void attn_stats(const __hip_bfloat16* __restrict__ qh,
        const __hip_bfloat16* __restrict__ kh, const float* __restrict__ validNeg,
        float* __restrict__ mrow, float* __restrict__ lrow)
{
    const int bh = blockIdx.x;
    const int w = threadIdx.x >> 6, lane = threadIdx.x & 63;
    const int m16 = lane & 15, quad = lane >> 4;
    const int qbase = (blockIdx.y << 6) + (w << 4);
    const __hip_bfloat16* qp = qh + ((((size_t)bh << 11) + qbase + m16) * HD_) + (quad << 3);
    const bf16x8_t a0 = load_bf8(qp);
    const bf16x8_t a1 = load_bf8(qp + 32);
    const float KS = SCALE_ * LOG2E_;
    float mr[4], lr[4];
    #pragma unroll
    for (int r = 0; r < 4; r++) { mr[r] = -1e30f; lr[r] = 0.f; }
    const __hip_bfloat16* kbase = kh + ((((size_t)bh << 11) + m16) * HD_) + (quad << 3);
    const float* vnp = validNeg + (bh << 11) + m16;
    const f32x4_t z = {0.f, 0.f, 0.f, 0.f};
    for (int kc = 0; kc < NS_; kc += 32) {
        const __hip_bfloat16* kp = kbase + (size_t)kc * HD_;
        bf16x8_t b00 = load_bf8(kp);
        bf16x8_t b01 = load_bf8(kp + 32);
        bf16x8_t b10 = load_bf8(kp + 16*HD_);
        bf16x8_t b11 = load_bf8(kp + 16*HD_ + 32);
        f32x4_t c0 = __builtin_amdgcn_mfma_f32_16x16x32_bf16(a0, b00, z, 0, 0, 0);
        c0 = __builtin_amdgcn_mfma_f32_16x16x32_bf16(a1, b01, c0, 0, 0, 0);
        f32x4_t c1 = __builtin_amdgcn_mfma_f32_16x16x32_bf16(a0, b10, z, 0, 0, 0);
        c1 = __builtin_amdgcn_mfma_f32_16x16x32_bf16(a1, b11, c1, 0, 0, 0);
        const float vn0 = vnp[kc] * LOG2E_;
        const float vn1 = vnp[kc + 16] * LOG2E_;
        #pragma unroll
        for (int r = 0; r < 4; r++) {
            const float s0 = c0[r]*KS + vn0;
            const float s1 = c1[r]*KS + vn1;
            const float mx = fmaxf(s0, s1);
            const float mn = fmaxf(mr[r], mx);
            lr[r] = lr[r]*exp2f(mr[r]-mn) + exp2f(s0-mn) + exp2f(s1-mn);
            mr[r] = mn;
        }
    }
    #pragma unroll
    for (int d = 1; d < 16; d <<= 1) {
        #pragma unroll
        for (int r = 0; r < 4; r++) {
            const float mo = __shfl_xor(mr[r], d, 64);
            const float lo = __shfl_xor(lr[r], d, 64);
            const float mn = fmaxf(mr[r], mo);
            lr[r] = lr[r]*exp2f(mr[r]-mn) + lo*exp2f(mo-mn);
            mr[r] = mn;
        }
    }
    if (m16 == 0) {
        #pragma unroll
        for (int r = 0; r < 4; r++) {
            const int row = qbase + (quad << 2) + r;
            mrow[(bh << 11) + row] = mr[r];
            lrow[(bh << 11) + row] = lr[r];
        }
    }
}

// ---------------------------------------------------------------------------
// K4b: PV pass. Recompute S, p = exp2(s - m), P -> LDS (A-frag layout),
// x = P @ V via MFMA with pre-transposed V. Output x in [B,N,C] layout.
// ---------------------------------------------------------------------------
__global__ __launch_bounds__(256) void attn_pv(const __hip_bfloat16* __restrict__ qh,
        const __hip_bfloat16* __restrict__ kh, const __hip_bfloat16* __restrict__ vT,
        const float* __restrict__ validNeg, const float* __restrict__ mrow,
        const float* __restrict__ lrow, float* __restrict__ xbuf)
{
    __shared__ __hip_bfloat16 pbuf[4][16*40];
    const int bh = blockIdx.x;
    const int w = threadIdx.x >> 6, lane = threadIdx.x & 63;
    const int m16 = lane & 15, quad = lane >> 4;
    const int qbase = (blockIdx.y << 6) + (w << 4);
    const __hip_bfloat16* qp = qh + ((((size_t)bh << 11) + qbase + m16) * HD_) + (quad << 3);
    const bf16x8_t a0 = load_bf8(qp);
    const bf16x8_t a1 = load_bf8(qp + 32);
    const float KS = SCALE_ * LOG2E_;
    float m2[4], li[4];
    #pragma unroll
    for (int r = 0; r < 4; r++) {
        const int row = qbase + (quad << 2) + r;
        m2[r] = mrow[(bh << 11) + row];
        li[r] = 1.0f / lrow[(bh << 11) + row];
    }
    const f32x4_t z = {0.f, 0.f, 0.f, 0.f};
    f32x4_t xacc[4];
    #pragma unroll
    for (int nt = 0; nt < 4; nt++) xacc[nt] = z;
    const __hip_bfloat16* kbase = kh + ((((size_t)bh << 11) + m16) * HD_) + (quad << 3);
    const float* vnp = validNeg + (bh << 11) + m16;
    __hip_bfloat16* pw = pbuf[w];
    for (int kc = 0; kc < NS_; kc += 32) {
        const __hip_bfloat16* kp = kbase + (size_t)kc * HD_;
        bf16x8_t b00 = load_bf8(kp);
        bf16x8_t b01 = load_bf8(kp + 32);
        bf16x8_t b10 = load_bf8(kp + 16*HD_);
        bf16x8_t b11 = load_bf8(kp + 16*HD_ + 32);
        f32x4_t c0 = __builtin_amdgcn_mfma_f32_16x16x32_bf16(a0, b00, z, 0, 0, 0);
        c0 = __builtin_amdgcn_mfma_f32_16x16x32_bf16(a1, b01, c0, 0, 0, 0);
        f32x4_t c1 = __builtin_amdgcn_mfma_f32_16x16x32_bf16(a0, b10, z, 0, 0, 0);
        c1 = __builtin_amdgcn_mfma_f32_16x16x32_bf16(a1, b11, c1, 0, 0, 0);
        const float vn0 = vnp[kc] * LOG2E_;
        const float vn1 = vnp[kc + 16] * LOG2E_;
        #pragma unroll
        for (int r = 0; r < 4; r++) {
            const float p0 = exp2f(c0[r]*KS + vn0 - m2[r]);
            const float p1 = exp2f(c1[r]*KS + vn1 - m2[r]);
            pw[(((quad<<2)+r)*40) + m16]      = __float2bfloat16(p0);
            pw[(((quad<<2)+r)*40) + 16 + m16] = __float2bfloat16(p1);
        }
        __syncthreads();
        const bf16x8_t pa = *reinterpret_cast<const bf16x8_t*>(&pw[m16*40 + (quad<<3)]);
        #pragma unroll
        for (int nt = 0; nt < 4; nt++) {
            const __hip_bfloat16* vp = vT + (((size_t)(bh*HD_) + (nt<<4) + m16) << 11) + kc + (quad<<3);
            bf16x8_t vb = load_bf8(vp);
            xacc[nt] = __builtin_amdgcn_mfma_f32_16x16x32_bf16(pa, vb, xacc[nt], 0, 0, 0);
        }
        __syncthreads();
    }
    const int b = bh >> 3, h = bh & 7;
    #pragma unroll
    for (int nt = 0; nt < 4; nt++) {
        #pragma unroll
        for (int r = 0; r < 4; r++) {
            const int row = qbase + (quad << 2) + r;
            xbuf[(((size_t)b << 11) + row) * C_ + (h << 6) + (nt << 4) + m16] = xacc[nt][r] * li[r];
        }
    }
}

// ---------------------------------------------------------------------------
extern "C" void kernel_launch(void* const* d_in, const int* in_sizes, int n_in,
                              void* d_out, int out_size, void* d_ws, size_t ws_size,
                              hipStream_t stream) {
    const float* q  = (const float*)d_in[0];
    const float* k  = (const float*)d_in[1];
    const float* v  = (const float*)d_in[2];
    const float* supp_valid = (const float*)d_in[3];
    const int*   supp_mask  = (const int*)d_in[4];
    const float* Wq = (const float*)d_in[5];
    const float* Wk = (const float*)d_in[6];
    const float* Wv = (const float*)d_in[7];
    const float* Wp = (const float*)d_in[8];
    float* out = (float*)d_out;

    char* p = (char*)d_ws;
    float* qh_f = (float*)p;           p += 8388608;   // [B,H,N,HD] f32
    float* kh_f = (float*)p;           p += 8388608;
    float* xbuf = (float*)p;           p += 8388608;   // [B,N,C] f32
    __hip_bfloat16* qh_b = (__hip_bfloat16*)p; p += 4194304;
    __hip_bfloat16* kh_b = (__hip_bfloat16*)p; p += 4194304;
    __hip_bfloat16* vT   = (__hip_bfloat16*)p; p += 4194304;  // [B,H,HD,NS]
    unsigned long long* q2kP = (unsigned long long*)p; p += 262144;
    unsigned long long* k2qP = (unsigned long long*)p; p += 262144;
    float* validNeg = (float*)p;       p += 131072;
    float* mrow = (float*)p;           p += 131072;
    float* lrow = (float*)p;           p += 131072;

    hipMemsetAsync(q2kP, 0, 262144 * 2, stream);

    dim3 gG(64, 8), bG(256);
    gemm512<<<gG, bG, 0, stream>>>(q, Wq, qh_f, qh_b, 0);
    gemm512<<<gG, bG, 0, stream>>>(k, Wk, kh_f, kh_b, 0);
    gemm512<<<gG, bG, 0, stream>>>(v, Wv, nullptr, vT, 2);

    dim3 gA(16, 4, 8);
    argmax_pass<<<gA, bG, 0, stream>>>(qh_f, kh_f, q2kP);
    argmax_pass<<<gA, bG, 0, stream>>>(kh_f, qh_f, k2qP);

    resolve<<<128, 256, 0, stream>>>(q2kP, k2qP, supp_mask, supp_valid, validNeg);

    dim3 gS(16, 32);
    attn_stats<<<gS, bG, 0, stream>>>(qh_b, kh_b, validNeg, mrow, lrow);
    attn_pv<<<gS, bG, 0, stream>>>(qh_b, kh_b, vT, validNeg, mrow, lrow, xbuf);

    gemm512<<<gG, bG, 0, stream>>>(xbuf, Wp, out, nullptr, 3);
}

// Round 2
// 601.828 us; speedup vs baseline: 1.0474x; 1.0474x over previous
//
#include <hip/hip_runtime.h>
#include <hip/hip_bf16.h>
#include <stdint.h>

#define B_ 2
#define H_ 8
#define N_ 2048
#define NS_ 2048
#define C_ 512
#define HD_ 64
#define SCALE_ 0.125f
#define NEG_ -10000.0f
#define LOG2E_ 1.4426950408889634f
#define MFIX_ 4.0f

typedef __bf16 bf16x8_t __attribute__((ext_vector_type(8)));
typedef float f32x4_t __attribute__((ext_vector_type(4)));

__device__ inline bf16x8_t load_bf8(const __hip_bfloat16* p) {
    union { uint4 u; bf16x8_t f; } cv;
    cv.u = *reinterpret_cast<const uint4*>(p);
    return cv.f;
}

// ---------------------------------------------------------------------------
// K1/K5: fp32 tiled GEMM  out[m,j] = sum_k A[m,k] * W[j,k]   (A @ W^T)
// mode 0/1: head-split fp32 + bf16 copy  (Q, K projections)
// mode 2:   transposed bf16 only [B,H,HD,NS] (V projection)
// mode 3:   flat fp32 (final output projection)
// ---------------------------------------------------------------------------
__global__ __launch_bounds__(256) void gemm512(const float* __restrict__ A,
        const float* __restrict__ W, float* __restrict__ outF,
        __hip_bfloat16* __restrict__ outB, int mode)
{
    __shared__ float As[16][68];
    __shared__ float Bs[16][68];
    const int t  = threadIdx.x;
    const int tx = t & 15, ty = t >> 4;
    const int bm = blockIdx.x << 6, bn = blockIdx.y << 6;
    const int lr = t >> 2, lk = (t & 3) << 2;
    const float* Ap = A + (size_t)(bm + lr) * C_ + lk;
    const float* Wp = W + (size_t)(bn + lr) * C_ + lk;
    float acc[4][4] = {};
    for (int k0 = 0; k0 < C_; k0 += 16) {
        float4 av = *reinterpret_cast<const float4*>(Ap + k0);
        float4 wv = *reinterpret_cast<const float4*>(Wp + k0);
        __syncthreads();
        As[lk+0][lr]=av.x; As[lk+1][lr]=av.y; As[lk+2][lr]=av.z; As[lk+3][lr]=av.w;
        Bs[lk+0][lr]=wv.x; Bs[lk+1][lr]=wv.y; Bs[lk+2][lr]=wv.z; Bs[lk+3][lr]=wv.w;
        __syncthreads();
        #pragma unroll
        for (int kk = 0; kk < 16; kk++) {
            float4 a = *reinterpret_cast<const float4*>(&As[kk][ty<<2]);
            float4 b = *reinterpret_cast<const float4*>(&Bs[kk][tx<<2]);
            acc[0][0] += a.x*b.x; acc[0][1] += a.x*b.y; acc[0][2] += a.x*b.z; acc[0][3] += a.x*b.w;
            acc[1][0] += a.y*b.x; acc[1][1] += a.y*b.y; acc[1][2] += a.y*b.z; acc[1][3] += a.y*b.w;
            acc[2][0] += a.z*b.x; acc[2][1] += a.z*b.y; acc[2][2] += a.z*b.z; acc[2][3] += a.z*b.w;
            acc[3][0] += a.w*b.x; acc[3][1] += a.w*b.y; acc[3][2] += a.w*b.z; acc[3][3] += a.w*b.w;
        }
    }
    #pragma unroll
    for (int i = 0; i < 4; i++) {
        const int gm = bm + (ty<<2) + i;
        const int b = gm >> 11, n = gm & 2047;
        #pragma unroll
        for (int j = 0; j < 4; j++) {
            const int gj = bn + (tx<<2) + j;
            const float val = acc[i][j];
            if (mode == 3) {
                outF[(size_t)gm * C_ + gj] = val;
            } else if (mode == 2) {
                const int h = gj >> 6, d = gj & 63;
                outB[(((size_t)(b*H_ + h)*HD_ + d) << 11) + n] = __float2bfloat16(val);
            } else {
                const int h = gj >> 6, d = gj & 63;
                const size_t idx = ((((size_t)(b*H_ + h)) << 11) + n) * HD_ + d;
                outF[idx] = val;
                outB[idx] = __float2bfloat16(val);
            }
        }
    }
}

// ---------------------------------------------------------------------------
// K2: FUSED fp32 argmax. S = qh @ kh^T computed once per (row,col); row-argmax
// (q2k) kept in registers; col-argmax (k2q) via wave fmax-butterfly + ballot
// (first/smallest row wins ties) + one packed atomicMax per column per wave.
// Packed tie-break: (ordered_float << 32) | ~idx  (smaller idx wins ties).
// ---------------------------------------------------------------------------
__device__ inline unsigned long long packArg(float v, int idx) {
    unsigned u = __float_as_uint(v);
    u = (u & 0x80000000u) ? ~u : (u | 0x80000000u);
    return ((unsigned long long)u << 32) | (unsigned)(~idx);
}

__global__ __launch_bounds__(256) void argmax_fused(const float* __restrict__ Af,
        const float* __restrict__ Bf, unsigned long long* __restrict__ rowP,
        unsigned long long* __restrict__ colP)
{
    // grid: (bh=16, rt=4, ct=16); block = 4 waves; wave covers 128 rows (2/lane)
    const int bh = blockIdx.x, rt = blockIdx.y, ct = blockIdx.z;
    const int t = threadIdx.x, w = t >> 6, lane = t & 63;
    const int rowbase = (rt << 9) + (w << 7);
    const int r0 = rowbase + lane;
    const int r1 = r0 + 64;
    const float* Abh = Af + (((size_t)bh) << 11) * HD_;
    const float* Bbh = Bf + (((size_t)bh) << 11) * HD_;
    float q0[64], q1[64];
    #pragma unroll
    for (int i = 0; i < 16; i++) {
        float4 v0 = *reinterpret_cast<const float4*>(Abh + (size_t)r0*HD_ + (i<<2));
        float4 v1 = *reinterpret_cast<const float4*>(Abh + (size_t)r1*HD_ + (i<<2));
        q0[(i<<2)+0]=v0.x; q0[(i<<2)+1]=v0.y; q0[(i<<2)+2]=v0.z; q0[(i<<2)+3]=v0.w;
        q1[(i<<2)+0]=v1.x; q1[(i<<2)+1]=v1.y; q1[(i<<2)+2]=v1.z; q1[(i<<2)+3]=v1.w;
    }
    __shared__ float Bs[64][68];
    float best0 = -3.4e38f, best1 = -3.4e38f;
    int bi0 = 0, bi1 = 0;
    for (int cc = 0; cc < 128; cc += 64) {
        const int cbase = (ct << 7) + cc;
        __syncthreads();
        {
            const int col = t >> 2, seg = t & 3;
            const float* src = Bbh + (size_t)(cbase + col)*HD_ + (seg<<4);
            const int dbase = seg << 4;
            #pragma unroll
            for (int j = 0; j < 4; j++) {
                float4 u = reinterpret_cast<const float4*>(src)[j];
                Bs[col][dbase + (j<<2) + 0] = u.x;
                Bs[col][dbase + (j<<2) + 1] = u.y;
                Bs[col][dbase + (j<<2) + 2] = u.z;
                Bs[col][dbase + (j<<2) + 3] = u.w;
            }
        }
        __syncthreads();
        for (int c = 0; c < 64; c++) {
            float a0 = 0.f, a1 = 0.f;
            #pragma unroll
            for (int d = 0; d < 64; d += 4) {
                float4 bv = *reinterpret_cast<const float4*>(&Bs[c][d]);
                a0 += q0[d+0]*bv.x; a0 += q0[d+1]*bv.y; a0 += q0[d+2]*bv.z; a0 += q0[d+3]*bv.w;
                a1 += q1[d+0]*bv.x; a1 += q1[d+1]*bv.y; a1 += q1[d+2]*bv.z; a1 += q1[d+3]*bv.w;
            }
            const int gc = cbase + c;
            if (a0 > best0) { best0 = a0; bi0 = gc; }
            if (a1 > best1) { best1 = a1; bi1 = gc; }
            // col-argmax: wave max over 128 rows, first-index tie-break
            float m = fmaxf(a0, a1);
            #pragma unroll
            for (int d = 1; d < 64; d <<= 1) m = fmaxf(m, __shfl_xor(m, d, 64));
            const unsigned long long mk0 = __ballot(a0 == m);
            const unsigned long long mk1 = __ballot(a1 == m);
            int rowIdx;
            if (mk0) rowIdx = rowbase + (__ffsll(mk0) - 1);
            else     rowIdx = rowbase + 64 + (__ffsll(mk1) - 1);
            if (lane == 0)
                atomicMax(colP + ((size_t)bh << 11) + gc, packArg(m, rowIdx));
        }
    }
    atomicMax(rowP + ((size_t)bh << 11) + r0, packArg(best0, bi0));
    atomicMax(rowP + ((size_t)bh << 11) + r1, packArg(best1, bi1));
}

// ---------------------------------------------------------------------------
// K3: cycle-consistency resolve -> validNeg[b,h,j] = valid * NEG
// ---------------------------------------------------------------------------
__global__ __launch_bounds__(256) void resolve(const unsigned long long* __restrict__ q2kP,
        const unsigned long long* __restrict__ k2qP, const int* __restrict__ supp_mask,
        const float* __restrict__ supp_valid, float* __restrict__ validNeg)
{
    const int t = blockIdx.x * 256 + threadIdx.x;      // 32768 = B*H*NS
    const int bh = t >> 11, j = t & 2047, b = bh >> 3;
    const unsigned k2q = 0xFFFFFFFFu - (unsigned)(k2qP[t] & 0xFFFFFFFFull);
    const unsigned rm  = 0xFFFFFFFFu - (unsigned)(q2kP[(bh << 11) + k2q] & 0xFFFFFFFFull);
    const int asso = supp_mask[(b << 11) + j] == supp_mask[(b << 11) + (int)rm];
    const float valid = asso ? supp_valid[(b << 11) + j] : 1.0f;
    validNeg[t] = valid * NEG_;
}

// ---------------------------------------------------------------------------
// K4a: masked softmax denominator with FIXED max (logits*log2e bounded by ~2,
// fixed m=4; masked cols -> exp2(-14431)=0 exactly). One wave = 16 q-rows.
// ---------------------------------------------------------------------------
__global__ __launch_bounds__(256) void attn_stats(const __hip_bfloat16* __restrict__ qh,
        const __hip_bfloat16* __restrict__ kh, const float* __restrict__ validNeg,
        float* __restrict__ lrow)
{
    const int bh = blockIdx.x;
    const int w = threadIdx.x >> 6, lane = threadIdx.x & 63;
    const int m16 = lane & 15, quad = lane >> 4;
    const int qbase = (blockIdx.y << 6) + (w << 4);
    const __hip_bfloat16* qp = qh + ((((size_t)bh << 11) + qbase + m16) * HD_) + (quad << 3);
    const bf16x8_t a0 = load_bf8(qp);
    const bf16x8_t a1 = load_bf8(qp + 32);
    const float KS = SCALE_ * LOG2E_;
    float lr[4] = {0.f, 0.f, 0.f, 0.f};
    const __hip_bfloat16* kbase = kh + ((((size_t)bh << 11) + m16) * HD_) + (quad << 3);
    const float* vnp = validNeg + (bh << 11) + m16;
    const f32x4_t z = {0.f, 0.f, 0.f, 0.f};
    for (int kc = 0; kc < NS_; kc += 32) {
        const __hip_bfloat16* kp = kbase + (size_t)kc * HD_;
        bf16x8_t b00 = load_bf8(kp);
        bf16x8_t b01 = load_bf8(kp + 32);
        bf16x8_t b10 = load_bf8(kp + 16*HD_);
        bf16x8_t b11 = load_bf8(kp + 16*HD_ + 32);
        f32x4_t c0 = __builtin_amdgcn_mfma_f32_16x16x32_bf16(a0, b00, z, 0, 0, 0);
        c0 = __builtin_amdgcn_mfma_f32_16x16x32_bf16(a1, b01, c0, 0, 0, 0);
        f32x4_t c1 = __builtin_amdgcn_mfma_f32_16x16x32_bf16(a0, b10, z, 0, 0, 0);
        c1 = __builtin_amdgcn_mfma_f32_16x16x32_bf16(a1, b11, c1, 0, 0, 0);
        const float vn0 = fmaf(vnp[kc],      LOG2E_, -MFIX_);
        const float vn1 = fmaf(vnp[kc + 16], LOG2E_, -MFIX_);
        #pragma unroll
        for (int r = 0; r < 4; r++)
            lr[r] += exp2f(fmaf(c0[r], KS, vn0)) + exp2f(fmaf(c1[r], KS, vn1));
    }
    #pragma unroll
    for (int d = 1; d < 16; d <<= 1) {
        #pragma unroll
        for (int r = 0; r < 4; r++) lr[r] += __shfl_xor(lr[r], d, 64);
    }
    if (m16 == 0) {
        #pragma unroll
        for (int r = 0; r < 4; r++)
            lrow[(bh << 11) + qbase + (quad << 2) + r] = lr[r];
    }
}

// ---------------------------------------------------------------------------
// K4b: PV pass. Recompute S, p = exp2(s - MFIX), P -> LDS (A-frag layout),
// x = P @ V via MFMA with pre-transposed V. Output x in [B,N,C] layout.
// ---------------------------------------------------------------------------
__global__ __launch_bounds__(256) void attn_pv(const __hip_bfloat16* __restrict__ qh,
        const __hip_bfloat16* __restrict__ kh, const __hip_bfloat16* __restrict__ vT,
        const float* __restrict__ validNeg, const float* __restrict__ lrow,
        float* __restrict__ xbuf)
{
    __shared__ __hip_bfloat16 pbuf[4][16*40];
    const int bh = blockIdx.x;
    const int w = threadIdx.x >> 6, lane = threadIdx.x & 63;
    const int m16 = lane & 15, quad = lane >> 4;
    const int qbase = (blockIdx.y << 6) + (w << 4);
    const __hip_bfloat16* qp = qh + ((((size_t)bh << 11) + qbase + m16) * HD_) + (quad << 3);
    const bf16x8_t a0 = load_bf8(qp);
    const bf16x8_t a1 = load_bf8(qp + 32);
    const float KS = SCALE_ * LOG2E_;
    float li[4];
    #pragma unroll
    for (int r = 0; r < 4; r++)
        li[r] = 1.0f / lrow[(bh << 11) + qbase + (quad << 2) + r];
    const f32x4_t z = {0.f, 0.f, 0.f, 0.f};
    f32x4_t xacc[4];
    #pragma unroll
    for (int nt = 0; nt < 4; nt++) xacc[nt] = z;
    const __hip_bfloat16* kbase = kh + ((((size_t)bh << 11) + m16) * HD_) + (quad << 3);
    const float* vnp = validNeg + (bh << 11) + m16;
    __hip_bfloat16* pw = pbuf[w];
    for (int kc = 0; kc < NS_; kc += 32) {
        const __hip_bfloat16* kp = kbase + (size_t)kc * HD_;
        bf16x8_t b00 = load_bf8(kp);
        bf16x8_t b01 = load_bf8(kp + 32);
        bf16x8_t b10 = load_bf8(kp + 16*HD_);
        bf16x8_t b11 = load_bf8(kp + 16*HD_ + 32);
        f32x4_t c0 = __builtin_amdgcn_mfma_f32_16x16x32_bf16(a0, b00, z, 0, 0, 0);
        c0 = __builtin_amdgcn_mfma_f32_16x16x32_bf16(a1, b01, c0, 0, 0, 0);
        f32x4_t c1 = __builtin_amdgcn_mfma_f32_16x16x32_bf16(a0, b10, z, 0, 0, 0);
        c1 = __builtin_amdgcn_mfma_f32_16x16x32_bf16(a1, b11, c1, 0, 0, 0);
        const float vn0 = fmaf(vnp[kc],      LOG2E_, -MFIX_);
        const float vn1 = fmaf(vnp[kc + 16], LOG2E_, -MFIX_);
        #pragma unroll
        for (int r = 0; r < 4; r++) {
            const float p0 = exp2f(fmaf(c0[r], KS, vn0));
            const float p1 = exp2f(fmaf(c1[r], KS, vn1));
            pw[(((quad<<2)+r)*40) + m16]      = __float2bfloat16(p0);
            pw[(((quad<<2)+r)*40) + 16 + m16] = __float2bfloat16(p1);
        }
        __syncthreads();
        const bf16x8_t pa = *reinterpret_cast<const bf16x8_t*>(&pw[m16*40 + (quad<<3)]);
        #pragma unroll
        for (int nt = 0; nt < 4; nt++) {
            const __hip_bfloat16* vp = vT + (((size_t)(bh*HD_) + (nt<<4) + m16) << 11) + kc + (quad<<3);
            bf16x8_t vb = load_bf8(vp);
            xacc[nt] = __builtin_amdgcn_mfma_f32_16x16x32_bf16(pa, vb, xacc[nt], 0, 0, 0);
        }
        __syncthreads();
    }
    const int b = bh >> 3, h = bh & 7;
    #pragma unroll
    for (int nt = 0; nt < 4; nt++) {
        #pragma unroll
        for (int r = 0; r < 4; r++) {
            const int row = qbase + (quad << 2) + r;
            xbuf[(((size_t)b << 11) + row) * C_ + (h << 6) + (nt << 4) + m16] = xacc[nt][r] * li[r];
        }
    }
}

// ---------------------------------------------------------------------------
extern "C" void kernel_launch(void* const* d_in, const int* in_sizes, int n_in,
                              void* d_out, int out_size, void* d_ws, size_t ws_size,
                              hipStream_t stream) {
    const float* q  = (const float*)d_in[0];
    const float* k  = (const float*)d_in[1];
    const float* v  = (const float*)d_in[2];
    const float* supp_valid = (const float*)d_in[3];
    const int*   supp_mask  = (const int*)d_in[4];
    const float* Wq = (const float*)d_in[5];
    const float* Wk = (const float*)d_in[6];
    const float* Wv = (const float*)d_in[7];
    const float* Wp = (const float*)d_in[8];
    float* out = (float*)d_out;

    char* p = (char*)d_ws;
    float* qh_f = (float*)p;           p += 8388608;   // [B,H,N,HD] f32
    float* kh_f = (float*)p;           p += 8388608;
    float* xbuf = (float*)p;           p += 8388608;   // [B,N,C] f32
    __hip_bfloat16* qh_b = (__hip_bfloat16*)p; p += 4194304;
    __hip_bfloat16* kh_b = (__hip_bfloat16*)p; p += 4194304;
    __hip_bfloat16* vT   = (__hip_bfloat16*)p; p += 4194304;  // [B,H,HD,NS]
    unsigned long long* q2kP = (unsigned long long*)p; p += 262144;
    unsigned long long* k2qP = (unsigned long long*)p; p += 262144;
    float* validNeg = (float*)p;       p += 131072;
    float* lrow = (float*)p;           p += 131072;

    hipMemsetAsync(q2kP, 0, 262144 * 2, stream);

    dim3 gG(64, 8), bG(256);
    gemm512<<<gG, bG, 0, stream>>>(q, Wq, qh_f, qh_b, 0);
    gemm512<<<gG, bG, 0, stream>>>(k, Wk, kh_f, kh_b, 0);
    gemm512<<<gG, bG, 0, stream>>>(v, Wv, nullptr, vT, 2);

    dim3 gF(16, 4, 16);
    argmax_fused<<<gF, bG, 0, stream>>>(qh_f, kh_f, q2kP, k2qP);

    resolve<<<128, 256, 0, stream>>>(q2kP, k2qP, supp_mask, supp_valid, validNeg);

    dim3 gS(16, 32);
    attn_stats<<<gS, bG, 0, stream>>>(qh_b, kh_b, validNeg, lrow);
    attn_pv<<<gS, bG, 0, stream>>>(qh_b, kh_b, vT, validNeg, lrow, xbuf);

    gemm512<<<gG, bG, 0, stream>>>(xbuf, Wp, out, nullptr, 3);
}

// Round 3
// 581.036 us; speedup vs baseline: 1.0849x; 1.0358x over previous
//
#include <hip/hip_runtime.h>
#include <hip/hip_bf16.h>
#include <stdint.h>

#define B_ 2
#define H_ 8
#define N_ 2048
#define NS_ 2048
#define C_ 512
#define HD_ 64
#define SCALE_ 0.125f
#define NEG_ -10000.0f
#define LOG2E_ 1.4426950408889634f
#define MFIX_ 4.0f

typedef __bf16 bf16x8_t __attribute__((ext_vector_type(8)));
typedef float f32x4_t __attribute__((ext_vector_type(4)));

#define MFMA16(a, b, c) __builtin_amdgcn_mfma_f32_16x16x32_bf16(a, b, c, 0, 0, 0)

__device__ inline bf16x8_t load_bf8(const __hip_bfloat16* p) {
    union { uint4 u; bf16x8_t f; } cv;
    cv.u = *reinterpret_cast<const uint4*>(p);
    return cv.f;
}

__device__ inline unsigned orderF(float v) {
    unsigned u = __float_as_uint(v);
    return (u & 0x80000000u) ? ~u : (u | 0x80000000u);
}
__device__ inline unsigned long long packVR(float v, int idx) {
    return ((unsigned long long)orderF(v) << 32) | (unsigned)(~idx);
}
__device__ inline unsigned long long max64(unsigned long long a, unsigned long long b) {
    return a > b ? a : b;
}
__device__ inline unsigned long long shflx64(unsigned long long x, int m) {
    unsigned lo = (unsigned)x, hi = (unsigned)(x >> 32);
    lo = __shfl_xor(lo, m, 64);
    hi = __shfl_xor(hi, m, 64);
    return ((unsigned long long)hi << 32) | lo;
}

// ---------------------------------------------------------------------------
// K1/K5: fp32 tiled GEMM  out[m,j] = sum_k A[m,k] * W[j,k]   (A @ W^T)
// mode 0/1: head-split 3-way bf16 split (hi/mid/lo) for the argmax+attn paths
// mode 2:   transposed bf16 only [B,H,HD,NS] (V projection)
// mode 3:   flat fp32 (final output projection)
// ---------------------------------------------------------------------------
__global__ __launch_bounds__(256) void gemm512(const float* __restrict__ A,
        const float* __restrict__ W, float* __restrict__ outF,
        __hip_bfloat16* __restrict__ outB, __hip_bfloat16* __restrict__ outM,
        __hip_bfloat16* __restrict__ outL, int mode)
{
    __shared__ float As[16][68];
    __shared__ float Bs[16][68];
    const int t  = threadIdx.x;
    const int tx = t & 15, ty = t >> 4;
    const int bm = blockIdx.x << 6, bn = blockIdx.y << 6;
    const int lr = t >> 2, lk = (t & 3) << 2;
    const float* Ap = A + (size_t)(bm + lr) * C_ + lk;
    const float* Wp = W + (size_t)(bn + lr) * C_ + lk;
    float acc[4][4] = {};
    for (int k0 = 0; k0 < C_; k0 += 16) {
        float4 av = *reinterpret_cast<const float4*>(Ap + k0);
        float4 wv = *reinterpret_cast<const float4*>(Wp + k0);
        __syncthreads();
        As[lk+0][lr]=av.x; As[lk+1][lr]=av.y; As[lk+2][lr]=av.z; As[lk+3][lr]=av.w;
        Bs[lk+0][lr]=wv.x; Bs[lk+1][lr]=wv.y; Bs[lk+2][lr]=wv.z; Bs[lk+3][lr]=wv.w;
        __syncthreads();
        #pragma unroll
        for (int kk = 0; kk < 16; kk++) {
            float4 a = *reinterpret_cast<const float4*>(&As[kk][ty<<2]);
            float4 b = *reinterpret_cast<const float4*>(&Bs[kk][tx<<2]);
            acc[0][0] += a.x*b.x; acc[0][1] += a.x*b.y; acc[0][2] += a.x*b.z; acc[0][3] += a.x*b.w;
            acc[1][0] += a.y*b.x; acc[1][1] += a.y*b.y; acc[1][2] += a.y*b.z; acc[1][3] += a.y*b.w;
            acc[2][0] += a.z*b.x; acc[2][1] += a.z*b.y; acc[2][2] += a.z*b.z; acc[2][3] += a.z*b.w;
            acc[3][0] += a.w*b.x; acc[3][1] += a.w*b.y; acc[3][2] += a.w*b.z; acc[3][3] += a.w*b.w;
        }
    }
    #pragma unroll
    for (int i = 0; i < 4; i++) {
        const int gm = bm + (ty<<2) + i;
        const int b = gm >> 11, n = gm & 2047;
        #pragma unroll
        for (int j = 0; j < 4; j++) {
            const int gj = bn + (tx<<2) + j;
            const float val = acc[i][j];
            if (mode == 3) {
                outF[(size_t)gm * C_ + gj] = val;
            } else if (mode == 2) {
                const int h = gj >> 6, d = gj & 63;
                outB[(((size_t)(b*H_ + h)*HD_ + d) << 11) + n] = __float2bfloat16(val);
            } else {
                const int h = gj >> 6, d = gj & 63;
                const size_t idx = ((((size_t)(b*H_ + h)) << 11) + n) * HD_ + d;
                const __hip_bfloat16 hh = __float2bfloat16(val);
                const float r1 = val - __bfloat162float(hh);
                const __hip_bfloat16 mm = __float2bfloat16(r1);
                const float r2 = r1 - __bfloat162float(mm);
                outB[idx] = hh;
                outM[idx] = mm;
                outL[idx] = __float2bfloat16(r2);
            }
        }
    }
}

// ---------------------------------------------------------------------------
// K2: MFMA 3-way-split argmax. S = qh @ kh^T via 6-term split-bf16 MFMA
// (error ~4e-8 << fp32 noise). Wave = 16 rows x all 2048 cols.
// Row-argmax: in-register + m16 butterfly -> direct store (no atomic).
// Col-argmax: reg-reduce + quad butterfly -> per-wave LDS strip (no k-loop
// barriers) -> block merge -> device atomicMax (packed u64 tie-break).
// ---------------------------------------------------------------------------
__global__ __launch_bounds__(256) void argmax_mfma(
        const __hip_bfloat16* __restrict__ qhi, const __hip_bfloat16* __restrict__ qmid,
        const __hip_bfloat16* __restrict__ qlo,
        const __hip_bfloat16* __restrict__ khi, const __hip_bfloat16* __restrict__ kmid,
        const __hip_bfloat16* __restrict__ klo,
        unsigned long long* __restrict__ rowP, unsigned long long* __restrict__ colP)
{
    __shared__ unsigned long long colbest[4 * 2048];   // 64 KB: [wave][col]
    const int bh = blockIdx.x;
    const int w = threadIdx.x >> 6, lane = threadIdx.x & 63;
    const int m16 = lane & 15, quad = lane >> 4;
    const int rowbase = (blockIdx.y << 6) + (w << 4);  // wave's first row
    const size_t qoff = (((size_t)bh << 11) + rowbase + m16) * HD_ + (quad << 3);
    const bf16x8_t a0h = load_bf8(qhi + qoff),  a1h = load_bf8(qhi + qoff + 32);
    const bf16x8_t a0m = load_bf8(qmid + qoff), a1m = load_bf8(qmid + qoff + 32);
    const bf16x8_t a0l = load_bf8(qlo + qoff),  a1l = load_bf8(qlo + qoff + 32);
    float bv[4] = {-3.4e38f, -3.4e38f, -3.4e38f, -3.4e38f};
    int   bc[4] = {0, 0, 0, 0};
    const f32x4_t z = {0.f, 0.f, 0.f, 0.f};
    const size_t kb = (((size_t)bh << 11) + m16) * HD_ + (quad << 3);

    for (int kc = 0; kc < NS_; kc += 32) {
        const size_t ko = kb + (size_t)kc * HD_;
        // tile0: keys kc+m16 ; tile1: keys kc+16+m16  (1024 = 16*HD_)
        bf16x8_t b00h = load_bf8(khi + ko),        b01h = load_bf8(khi + ko + 32);
        bf16x8_t b10h = load_bf8(khi + ko + 1024), b11h = load_bf8(khi + ko + 1056);
        bf16x8_t b00m = load_bf8(kmid + ko),        b01m = load_bf8(kmid + ko + 32);
        bf16x8_t b10m = load_bf8(kmid + ko + 1024), b11m = load_bf8(kmid + ko + 1056);
        bf16x8_t b00l = load_bf8(klo + ko),        b01l = load_bf8(klo + ko + 32);
        bf16x8_t b10l = load_bf8(klo + ko + 1024), b11l = load_bf8(klo + ko + 1056);
        // tile0, K-half 0 and 1 as independent chains
        f32x4_t ca = MFMA16(a0h, b00h, z);
        ca = MFMA16(a0h, b00m, ca); ca = MFMA16(a0m, b00h, ca);
        ca = MFMA16(a0h, b00l, ca); ca = MFMA16(a0l, b00h, ca);
        ca = MFMA16(a0m, b00m, ca);
        f32x4_t cb = MFMA16(a1h, b01h, z);
        cb = MFMA16(a1h, b01m, cb); cb = MFMA16(a1m, b01h, cb);
        cb = MFMA16(a1h, b01l, cb); cb = MFMA16(a1l, b01h, cb);
        cb = MFMA16(a1m, b01m, cb);
        // tile1
        f32x4_t cc = MFMA16(a0h, b10h, z);
        cc = MFMA16(a0h, b10m, cc); cc = MFMA16(a0m, b10h, cc);
        cc = MFMA16(a0h, b10l, cc); cc = MFMA16(a0l, b10h, cc);
        cc = MFMA16(a0m, b10m, cc);
        f32x4_t cd = MFMA16(a1h, b11h, z);
        cd = MFMA16(a1h, b11m, cd); cd = MFMA16(a1m, b11h, cd);
        cd = MFMA16(a1h, b11l, cd); cd = MFMA16(a1l, b11h, cd);
        cd = MFMA16(a1m, b11m, cd);
        const f32x4_t c0 = ca + cb;
        const f32x4_t c1 = cc + cd;
        // ---- row argmax (strict >, earlier col wins ties) ----
        #pragma unroll
        for (int r = 0; r < 4; r++) {
            if (c0[r] > bv[r]) { bv[r] = c0[r]; bc[r] = kc + m16; }
            if (c1[r] > bv[r]) { bv[r] = c1[r]; bc[r] = kc + 16 + m16; }
        }
        // ---- col argmax: reduce 4 regs (rows), then quad butterfly ----
        float v0 = c0[0]; int i0 = 0;
        if (c0[1] > v0) { v0 = c0[1]; i0 = 1; }
        if (c0[2] > v0) { v0 = c0[2]; i0 = 2; }
        if (c0[3] > v0) { v0 = c0[3]; i0 = 3; }
        float v1 = c1[0]; int i1 = 0;
        if (c1[1] > v1) { v1 = c1[1]; i1 = 1; }
        if (c1[2] > v1) { v1 = c1[2]; i1 = 2; }
        if (c1[3] > v1) { v1 = c1[3]; i1 = 3; }
        unsigned long long p0 = packVR(v0, rowbase + (quad << 2) + i0);
        unsigned long long p1 = packVR(v1, rowbase + (quad << 2) + i1);
        p0 = max64(p0, shflx64(p0, 16)); p0 = max64(p0, shflx64(p0, 32));
        p1 = max64(p1, shflx64(p1, 16)); p1 = max64(p1, shflx64(p1, 32));
        if (quad == 0)      colbest[(w << 11) + kc + m16]      = p0;
        else if (quad == 1) colbest[(w << 11) + kc + 16 + m16] = p1;
    }
    // ---- row results: butterfly over m16, single writer per row ----
    #pragma unroll
    for (int r = 0; r < 4; r++) {
        unsigned long long pr = packVR(bv[r], bc[r]);
        pr = max64(pr, shflx64(pr, 1));
        pr = max64(pr, shflx64(pr, 2));
        pr = max64(pr, shflx64(pr, 4));
        pr = max64(pr, shflx64(pr, 8));
        if (m16 == 0)
            rowP[((size_t)bh << 11) + rowbase + (quad << 2) + r] = pr;
    }
    // ---- block merge of col candidates + device atomic ----
    __syncthreads();
    for (int c = threadIdx.x; c < NS_; c += 256) {
        unsigned long long m = colbest[c];
        m = max64(m, colbest[2048 + c]);
        m = max64(m, colbest[4096 + c]);
        m = max64(m, colbest[6144 + c]);
        atomicMax(colP + ((size_t)bh << 11) + c, m);
    }
}

// ---------------------------------------------------------------------------
// K3: cycle-consistency resolve -> validNeg[b,h,j] = valid * NEG
// ---------------------------------------------------------------------------
__global__ __launch_bounds__(256) void resolve(const unsigned long long* __restrict__ q2kP,
        const unsigned long long* __restrict__ k2qP, const int* __restrict__ supp_mask,
        const float* __restrict__ supp_valid, float* __restrict__ validNeg)
{
    const int t = blockIdx.x * 256 + threadIdx.x;      // 32768 = B*H*NS
    const int bh = t >> 11, j = t & 2047, b = bh >> 3;
    const unsigned k2q = 0xFFFFFFFFu - (unsigned)(k2qP[t] & 0xFFFFFFFFull);
    const unsigned rm  = 0xFFFFFFFFu - (unsigned)(q2kP[(bh << 11) + k2q] & 0xFFFFFFFFull);
    const int asso = supp_mask[(b << 11) + j] == supp_mask[(b << 11) + (int)rm];
    const float valid = asso ? supp_valid[(b << 11) + j] : 1.0f;
    validNeg[t] = valid * NEG_;
}

// ---------------------------------------------------------------------------
// K4a: masked softmax denominator with FIXED max (logits*log2e bounded by ~2,
// fixed m=4; masked cols -> exp2(-14431)=0 exactly). One wave = 16 q-rows.
// ---------------------------------------------------------------------------
__global__ __launch_bounds__(256) void attn_stats(const __hip_bfloat16* __restrict__ qh,
        const __hip_bfloat16* __restrict__ kh, const float* __restrict__ validNeg,
        float* __restrict__ lrow)
{
    const int bh = blockIdx.x;
    const int w = threadIdx.x >> 6, lane = threadIdx.x & 63;
    const int m16 = lane & 15, quad = lane >> 4;
    const int qbase = (blockIdx.y << 6) + (w << 4);
    const __hip_bfloat16* qp = qh + ((((size_t)bh << 11) + qbase + m16) * HD_) + (quad << 3);
    const bf16x8_t a0 = load_bf8(qp);
    const bf16x8_t a1 = load_bf8(qp + 32);
    const float KS = SCALE_ * LOG2E_;
    float lr[4] = {0.f, 0.f, 0.f, 0.f};
    const __hip_bfloat16* kbase = kh + ((((size_t)bh << 11) + m16) * HD_) + (quad << 3);
    const float* vnp = validNeg + (bh << 11) + m16;
    const f32x4_t z = {0.f, 0.f, 0.f, 0.f};
    for (int kc = 0; kc < NS_; kc += 32) {
        const __hip_bfloat16* kp = kbase + (size_t)kc * HD_;
        bf16x8_t b00 = load_bf8(kp);
        bf16x8_t b01 = load_bf8(kp + 32);
        bf16x8_t b10 = load_bf8(kp + 16*HD_);
        bf16x8_t b11 = load_bf8(kp + 16*HD_ + 32);
        f32x4_t c0 = MFMA16(a0, b00, z);
        c0 = MFMA16(a1, b01, c0);
        f32x4_t c1 = MFMA16(a0, b10, z);
        c1 = MFMA16(a1, b11, c1);
        const float vn0 = fmaf(vnp[kc],      LOG2E_, -MFIX_);
        const float vn1 = fmaf(vnp[kc + 16], LOG2E_, -MFIX_);
        #pragma unroll
        for (int r = 0; r < 4; r++)
            lr[r] += exp2f(fmaf(c0[r], KS, vn0)) + exp2f(fmaf(c1[r], KS, vn1));
    }
    #pragma unroll
    for (int d = 1; d < 16; d <<= 1) {
        #pragma unroll
        for (int r = 0; r < 4; r++) lr[r] += __shfl_xor(lr[r], d, 64);
    }
    if (m16 == 0) {
        #pragma unroll
        for (int r = 0; r < 4; r++)
            lrow[(bh << 11) + qbase + (quad << 2) + r] = lr[r];
    }
}

// ---------------------------------------------------------------------------
// K4b: PV pass. Recompute S, p = exp2(s - MFIX), P -> LDS (A-frag layout),
// x = P @ V via MFMA with pre-transposed V. Output x in [B,N,C] layout.
// ---------------------------------------------------------------------------
__global__ __launch_bounds__(256) void attn_pv(const __hip_bfloat16* __restrict__ qh,
        const __hip_bfloat16* __restrict__ kh, const __hip_bfloat16* __restrict__ vT,
        const float* __restrict__ validNeg, const float* __restrict__ lrow,
        float* __restrict__ xbuf)
{
    __shared__ __hip_bfloat16 pbuf[4][16*40];
    const int bh = blockIdx.x;
    const int w = threadIdx.x >> 6, lane = threadIdx.x & 63;
    const int m16 = lane & 15, quad = lane >> 4;
    const int qbase = (blockIdx.y << 6) + (w << 4);
    const __hip_bfloat16* qp = qh + ((((size_t)bh << 11) + qbase + m16) * HD_) + (quad << 3);
    const bf16x8_t a0 = load_bf8(qp);
    const bf16x8_t a1 = load_bf8(qp + 32);
    const float KS = SCALE_ * LOG2E_;
    float li[4];
    #pragma unroll
    for (int r = 0; r < 4; r++)
        li[r] = 1.0f / lrow[(bh << 11) + qbase + (quad << 2) + r];
    const f32x4_t z = {0.f, 0.f, 0.f, 0.f};
    f32x4_t xacc[4];
    #pragma unroll
    for (int nt = 0; nt < 4; nt++) xacc[nt] = z;
    const __hip_bfloat16* kbase = kh + ((((size_t)bh << 11) + m16) * HD_) + (quad << 3);
    const float* vnp = validNeg + (bh << 11) + m16;
    __hip_bfloat16* pw = pbuf[w];
    for (int kc = 0; kc < NS_; kc += 32) {
        const __hip_bfloat16* kp = kbase + (size_t)kc * HD_;
        bf16x8_t b00 = load_bf8(kp);
        bf16x8_t b01 = load_bf8(kp + 32);
        bf16x8_t b10 = load_bf8(kp + 16*HD_);
        bf16x8_t b11 = load_bf8(kp + 16*HD_ + 32);
        f32x4_t c0 = MFMA16(a0, b00, z);
        c0 = MFMA16(a1, b01, c0);
        f32x4_t c1 = MFMA16(a0, b10, z);
        c1 = MFMA16(a1, b11, c1);
        const float vn0 = fmaf(vnp[kc],      LOG2E_, -MFIX_);
        const float vn1 = fmaf(vnp[kc + 16], LOG2E_, -MFIX_);
        #pragma unroll
        for (int r = 0; r < 4; r++) {
            const float p0 = exp2f(fmaf(c0[r], KS, vn0));
            const float p1 = exp2f(fmaf(c1[r], KS, vn1));
            pw[(((quad<<2)+r)*40) + m16]      = __float2bfloat16(p0);
            pw[(((quad<<2)+r)*40) + 16 + m16] = __float2bfloat16(p1);
        }
        __syncthreads();
        const bf16x8_t pa = *reinterpret_cast<const bf16x8_t*>(&pw[m16*40 + (quad<<3)]);
        #pragma unroll
        for (int nt = 0; nt < 4; nt++) {
            const __hip_bfloat16* vp = vT + (((size_t)(bh*HD_) + (nt<<4) + m16) << 11) + kc + (quad<<3);
            bf16x8_t vb = load_bf8(vp);
            xacc[nt] = MFMA16(pa, vb, xacc[nt]);
        }
        __syncthreads();
    }
    const int b = bh >> 3, h = bh & 7;
    #pragma unroll
    for (int nt = 0; nt < 4; nt++) {
        #pragma unroll
        for (int r = 0; r < 4; r++) {
            const int row = qbase + (quad << 2) + r;
            xbuf[(((size_t)b << 11) + row) * C_ + (h << 6) + (nt << 4) + m16] = xacc[nt][r] * li[r];
        }
    }
}

// ---------------------------------------------------------------------------
extern "C" void kernel_launch(void* const* d_in, const int* in_sizes, int n_in,
                              void* d_out, int out_size, void* d_ws, size_t ws_size,
                              hipStream_t stream) {
    const float* q  = (const float*)d_in[0];
    const float* k  = (const float*)d_in[1];
    const float* v  = (const float*)d_in[2];
    const float* supp_valid = (const float*)d_in[3];
    const int*   supp_mask  = (const int*)d_in[4];
    const float* Wq = (const float*)d_in[5];
    const float* Wk = (const float*)d_in[6];
    const float* Wv = (const float*)d_in[7];
    const float* Wp = (const float*)d_in[8];
    float* out = (float*)d_out;

    char* p = (char*)d_ws;
    float* xbuf = (float*)p;                   p += 8388608;   // [B,N,C] f32
    __hip_bfloat16* qhi  = (__hip_bfloat16*)p; p += 4194304;   // [B,H,N,HD] bf16 splits
    __hip_bfloat16* qmid = (__hip_bfloat16*)p; p += 4194304;
    __hip_bfloat16* qlo  = (__hip_bfloat16*)p; p += 4194304;
    __hip_bfloat16* khi  = (__hip_bfloat16*)p; p += 4194304;
    __hip_bfloat16* kmid = (__hip_bfloat16*)p; p += 4194304;
    __hip_bfloat16* klo  = (__hip_bfloat16*)p; p += 4194304;
    __hip_bfloat16* vT   = (__hip_bfloat16*)p; p += 4194304;   // [B,H,HD,NS]
    unsigned long long* q2kP = (unsigned long long*)p; p += 262144;
    unsigned long long* k2qP = (unsigned long long*)p; p += 262144;
    float* validNeg = (float*)p;               p += 131072;
    float* lrow = (float*)p;                   p += 131072;

    hipMemsetAsync(k2qP, 0, 262144, stream);   // colP needs zero init

    dim3 gG(64, 8), bG(256);
    gemm512<<<gG, bG, 0, stream>>>(q, Wq, nullptr, qhi, qmid, qlo, 0);
    gemm512<<<gG, bG, 0, stream>>>(k, Wk, nullptr, khi, kmid, klo, 0);
    gemm512<<<gG, bG, 0, stream>>>(v, Wv, nullptr, vT, nullptr, nullptr, 2);

    dim3 gF(16, 32);
    argmax_mfma<<<gF, bG, 0, stream>>>(qhi, qmid, qlo, khi, kmid, klo, q2kP, k2qP);

    resolve<<<128, 256, 0, stream>>>(q2kP, k2qP, supp_mask, supp_valid, validNeg);

    dim3 gS(16, 32);
    attn_stats<<<gS, bG, 0, stream>>>(qhi, khi, validNeg, lrow);
    attn_pv<<<gS, bG, 0, stream>>>(qhi, khi, vT, validNeg, lrow, xbuf);

    gemm512<<<gG, bG, 0, stream>>>(xbuf, Wp, out, nullptr, nullptr, nullptr, 3);
}

// Round 4
// 348.255 us; speedup vs baseline: 1.8100x; 1.6684x over previous
//
#include <hip/hip_runtime.h>
#include <hip/hip_bf16.h>
#include <stdint.h>

#define H_ 8
#define NS_ 2048
#define C_ 512
#define HD_ 64
#define SCALE_ 0.125f
#define NEG_ -10000.0f
#define LOG2E_ 1.4426950408889634f
#define MFIX_ 4.0f

typedef _Float16 f16x8_t __attribute__((ext_vector_type(8)));
typedef float f32x4_t __attribute__((ext_vector_type(4)));

#define MFMAH(a, b, c) __builtin_amdgcn_mfma_f32_16x16x32_f16(a, b, c, 0, 0, 0)

__device__ inline f16x8_t load_h8(const _Float16* p) {
    return *reinterpret_cast<const f16x8_t*>(p);
}

// async global->LDS, 16B per lane; LDS dest = uniform base + lane*16
__device__ inline void gload_lds16(const void* g, void* l) {
    __builtin_amdgcn_global_load_lds(
        (const __attribute__((address_space(1))) unsigned int*)g,
        (__attribute__((address_space(3))) unsigned int*)l, 16, 0, 0);
}

__device__ inline unsigned orderF(float v) {
    unsigned u = __float_as_uint(v);
    return (u & 0x80000000u) ? ~u : (u | 0x80000000u);
}
__device__ inline unsigned long long packVR(float v, int idx) {
    return ((unsigned long long)orderF(v) << 32) | (unsigned)(~idx);
}
__device__ inline unsigned long long max64(unsigned long long a, unsigned long long b) {
    return a > b ? a : b;
}
__device__ inline unsigned long long shflx64(unsigned long long x, int m) {
    unsigned lo = (unsigned)x, hi = (unsigned)(x >> 32);
    lo = __shfl_xor(lo, m, 64);
    hi = __shfl_xor(hi, m, 64);
    return ((unsigned long long)hi << 32) | lo;
}

// ---------------------------------------------------------------------------
// K1/K5: fp32 tiled GEMM  out[m,j] = sum_k A[m,k] * W[j,k]   (A @ W^T)
// mode 0: head-split 2-way fp16 split (hi/lo) [bh][n][64]
// mode 2: fp16 V, tiled [bh][chunk=n>>5][d][n&31]
// mode 3: flat fp32 (final output projection)
// ---------------------------------------------------------------------------
__global__ __launch_bounds__(256) void gemm512(const float* __restrict__ A,
        const float* __restrict__ W, float* __restrict__ outF,
        _Float16* __restrict__ o1, _Float16* __restrict__ o2, int mode)
{
    __shared__ float As[16][68];
    __shared__ float Bs[16][68];
    const int t  = threadIdx.x;
    const int tx = t & 15, ty = t >> 4;
    const int bm = blockIdx.x << 6, bn = blockIdx.y << 6;
    const int lr = t >> 2, lk = (t & 3) << 2;
    const float* Ap = A + (size_t)(bm + lr) * C_ + lk;
    const float* Wp = W + (size_t)(bn + lr) * C_ + lk;
    float acc[4][4] = {};
    for (int k0 = 0; k0 < C_; k0 += 16) {
        float4 av = *reinterpret_cast<const float4*>(Ap + k0);
        float4 wv = *reinterpret_cast<const float4*>(Wp + k0);
        __syncthreads();
        As[lk+0][lr]=av.x; As[lk+1][lr]=av.y; As[lk+2][lr]=av.z; As[lk+3][lr]=av.w;
        Bs[lk+0][lr]=wv.x; Bs[lk+1][lr]=wv.y; Bs[lk+2][lr]=wv.z; Bs[lk+3][lr]=wv.w;
        __syncthreads();
        #pragma unroll
        for (int kk = 0; kk < 16; kk++) {
            float4 a = *reinterpret_cast<const float4*>(&As[kk][ty<<2]);
            float4 b = *reinterpret_cast<const float4*>(&Bs[kk][tx<<2]);
            acc[0][0] += a.x*b.x; acc[0][1] += a.x*b.y; acc[0][2] += a.x*b.z; acc[0][3] += a.x*b.w;
            acc[1][0] += a.y*b.x; acc[1][1] += a.y*b.y; acc[1][2] += a.y*b.z; acc[1][3] += a.y*b.w;
            acc[2][0] += a.z*b.x; acc[2][1] += a.z*b.y; acc[2][2] += a.z*b.z; acc[2][3] += a.z*b.w;
            acc[3][0] += a.w*b.x; acc[3][1] += a.w*b.y; acc[3][2] += a.w*b.z; acc[3][3] += a.w*b.w;
        }
    }
    #pragma unroll
    for (int i = 0; i < 4; i++) {
        const int gm = bm + (ty<<2) + i;
        const int b = gm >> 11, n = gm & 2047;
        #pragma unroll
        for (int j = 0; j < 4; j++) {
            const int gj = bn + (tx<<2) + j;
            const float val = acc[i][j];
            if (mode == 3) {
                outF[(size_t)gm * C_ + gj] = val;
            } else if (mode == 2) {
                const int h = gj >> 6, d = gj & 63;
                const int bh = b * H_ + h;
                o1[(((size_t)(bh*64 + (n>>5)))*64 + d)*32 + (n&31)] = (_Float16)val;
            } else {
                const int h = gj >> 6, d = gj & 63;
                const size_t idx = ((((size_t)(b*H_ + h)) << 11) + n) * HD_ + d;
                const _Float16 hh = (_Float16)val;
                const float r1 = val - (float)hh;
                o1[idx] = hh;
                o2[idx] = (_Float16)r1;
            }
        }
    }
}

// ---------------------------------------------------------------------------
// K2: MFMA fp16 2-way-split argmax (terms hh+lh+hl; residual ~2e-7 << fp32
// noise). XCD-pinned blocks (bh 2x,2x+1 -> XCD x); K chunk (both splits)
// staged in LDS via global_load_lds with XOR block swizzle (conflict-free
// b128 readback). Row-argmax in-register; col-argmax quad-butterfly ->
// LDS atomicMax -> one global atomicMax per col per block.
// ---------------------------------------------------------------------------
__global__ __launch_bounds__(256) void argmax_mfma(
        const _Float16* __restrict__ qhi, const _Float16* __restrict__ qlo,
        const _Float16* __restrict__ khi, const _Float16* __restrict__ klo,
        unsigned long long* __restrict__ rowP, unsigned long long* __restrict__ colP)
{
    __shared__ __attribute__((aligned(16))) _Float16 Ksh[2][2048];  // 8 KB
    __shared__ unsigned long long colbest[NS_];                     // 16 KB
    const int bx = blockIdx.x;
    const int bh = ((bx & 7) << 1) | ((bx >> 3) >> 5);
    const int rt = (bx >> 3) & 31;
    const int t = threadIdx.x, w = t >> 6, lane = t & 63;
    const int m16 = lane & 15, quad = lane >> 4;
    const int rowbase = (rt << 6) + (w << 4);
    const size_t qoff = ((((size_t)bh << 11) + rowbase + m16) << 6) + (quad << 3);
    const f16x8_t a0h = load_h8(qhi + qoff), a1h = load_h8(qhi + qoff + 32);
    const f16x8_t a0l = load_h8(qlo + qoff), a1l = load_h8(qlo + qoff + 32);
    // staging lane constants: image offset = row*128B + blk*16B, swizzled slot
    const int krow = lane >> 3;                    // 0..7 within 1KB piece
    const int kblk = (lane & 7) ^ (krow & 7);      // source block for this slot
    for (int c = t; c < NS_; c += 256) colbest[c] = 0;
    float bv[4] = {-3.4e38f, -3.4e38f, -3.4e38f, -3.4e38f};
    int   bc[4] = {0, 0, 0, 0};
    const f32x4_t z = {0.f, 0.f, 0.f, 0.f};
    const size_t kbel = ((size_t)bh << 11) * HD_;
    const int e = m16 & 7;
    const int s00 = ((quad) ^ e) << 3, s01 = ((4 + quad) ^ e) << 3;

    for (int kc = 0; kc < NS_; kc += 32) {
        __syncthreads();
        {
            const size_t ce = kbel + (size_t)kc * HD_;
            #pragma unroll
            for (int ci = 0; ci < 2; ci++) {
                const int call = (w << 1) + ci;
                const int j = call & 3, s = call >> 2;
                const _Float16* src = (s ? klo : khi) + ce + ((j * 8 + krow) << 6) + (kblk << 3);
                gload_lds16(src, &Ksh[s][j << 9]);
            }
        }
        __syncthreads();
        const f16x8_t b00h = load_h8(&Ksh[0][(m16 << 6) + s00]);
        const f16x8_t b01h = load_h8(&Ksh[0][(m16 << 6) + s01]);
        const f16x8_t b10h = load_h8(&Ksh[0][((16 + m16) << 6) + s00]);
        const f16x8_t b11h = load_h8(&Ksh[0][((16 + m16) << 6) + s01]);
        const f16x8_t b00l = load_h8(&Ksh[1][(m16 << 6) + s00]);
        const f16x8_t b01l = load_h8(&Ksh[1][(m16 << 6) + s01]);
        const f16x8_t b10l = load_h8(&Ksh[1][((16 + m16) << 6) + s00]);
        const f16x8_t b11l = load_h8(&Ksh[1][((16 + m16) << 6) + s01]);
        f32x4_t ca = MFMAH(a0h, b00h, z); ca = MFMAH(a0l, b00h, ca); ca = MFMAH(a0h, b00l, ca);
        f32x4_t cb = MFMAH(a1h, b01h, z); cb = MFMAH(a1l, b01h, cb); cb = MFMAH(a1h, b01l, cb);
        f32x4_t cc = MFMAH(a0h, b10h, z); cc = MFMAH(a0l, b10h, cc); cc = MFMAH(a0h, b10l, cc);
        f32x4_t cd = MFMAH(a1h, b11h, z); cd = MFMAH(a1l, b11h, cd); cd = MFMAH(a1h, b11l, cd);
        const f32x4_t c0 = ca + cb, c1 = cc + cd;
        // row argmax (strict >, earlier col wins)
        #pragma unroll
        for (int r = 0; r < 4; r++) {
            if (c0[r] > bv[r]) { bv[r] = c0[r]; bc[r] = kc + m16; }
            if (c1[r] > bv[r]) { bv[r] = c1[r]; bc[r] = kc + 16 + m16; }
        }
        // col argmax: reduce rows in-lane, quad butterfly, LDS atomic
        float v0 = c0[0]; int i0 = 0;
        if (c0[1] > v0) { v0 = c0[1]; i0 = 1; }
        if (c0[2] > v0) { v0 = c0[2]; i0 = 2; }
        if (c0[3] > v0) { v0 = c0[3]; i0 = 3; }
        float v1 = c1[0]; int i1 = 0;
        if (c1[1] > v1) { v1 = c1[1]; i1 = 1; }
        if (c1[2] > v1) { v1 = c1[2]; i1 = 2; }
        if (c1[3] > v1) { v1 = c1[3]; i1 = 3; }
        unsigned long long p0 = packVR(v0, rowbase + (quad << 2) + i0);
        unsigned long long p1 = packVR(v1, rowbase + (quad << 2) + i1);
        p0 = max64(p0, shflx64(p0, 16)); p0 = max64(p0, shflx64(p0, 32));
        p1 = max64(p1, shflx64(p1, 16)); p1 = max64(p1, shflx64(p1, 32));
        if (quad == 0)      atomicMax(&colbest[kc + m16], p0);
        else if (quad == 1) atomicMax(&colbest[kc + 16 + m16], p1);
    }
    // row writeout
    #pragma unroll
    for (int r = 0; r < 4; r++) {
        unsigned long long pr = packVR(bv[r], bc[r]);
        pr = max64(pr, shflx64(pr, 1));
        pr = max64(pr, shflx64(pr, 2));
        pr = max64(pr, shflx64(pr, 4));
        pr = max64(pr, shflx64(pr, 8));
        if (m16 == 0)
            rowP[((size_t)bh << 11) + rowbase + (quad << 2) + r] = pr;
    }
    __syncthreads();
    for (int c = t; c < NS_; c += 256)
        atomicMax(colP + ((size_t)bh << 11) + c, colbest[c]);
}

// ---------------------------------------------------------------------------
// K3: cycle-consistency resolve -> vn[b,h,j] = valid*NEG*LOG2E - MFIX
// ---------------------------------------------------------------------------
__global__ __launch_bounds__(256) void resolve(const unsigned long long* __restrict__ q2kP,
        const unsigned long long* __restrict__ k2qP, const int* __restrict__ supp_mask,
        const float* __restrict__ supp_valid, float* __restrict__ vn)
{
    const int t = blockIdx.x * 256 + threadIdx.x;      // 32768 = B*H*NS
    const int bh = t >> 11, j = t & 2047, b = bh >> 3;
    const unsigned k2q = 0xFFFFFFFFu - (unsigned)(k2qP[t] & 0xFFFFFFFFull);
    const unsigned rm  = 0xFFFFFFFFu - (unsigned)(q2kP[(bh << 11) + k2q] & 0xFFFFFFFFull);
    const int asso = supp_mask[(b << 11) + j] == supp_mask[(b << 11) + (int)rm];
    const float valid = asso ? supp_valid[(b << 11) + j] : 1.0f;
    vn[t] = fmaf(valid, NEG_ * LOG2E_, -MFIX_);
}

// ---------------------------------------------------------------------------
// K4: fused attention. S via fp16-hi MFMA, p = exp2(s + vn) (fixed-max),
// l accumulated in-pass, P -> per-wave LDS strip -> PV MFMA (staged V),
// divide by l at the end. K and V chunks LDS-staged (XOR swizzle),
// vn staged once. XCD-pinned blocks.
// ---------------------------------------------------------------------------
__global__ __launch_bounds__(256) void attn_pv(
        const _Float16* __restrict__ qh, const _Float16* __restrict__ kh,
        const _Float16* __restrict__ vT, const float* __restrict__ vnG,
        float* __restrict__ xbuf)
{
    __shared__ __attribute__((aligned(16))) _Float16 Ksh[2048];     // 4 KB
    __shared__ __attribute__((aligned(16))) _Float16 Vsh[2048];     // 4 KB
    __shared__ float vnL[NS_];                                      // 8 KB
    __shared__ __attribute__((aligned(16))) _Float16 pbuf[4][16*40];// 5 KB
    const int bx = blockIdx.x;
    const int bh = ((bx & 7) << 1) | ((bx >> 3) >> 5);
    const int rt = (bx >> 3) & 31;
    const int t = threadIdx.x, w = t >> 6, lane = t & 63;
    const int m16 = lane & 15, quad = lane >> 4;
    const int qbase = (rt << 6) + (w << 4);
    const size_t qoff = ((((size_t)bh << 11) + qbase + m16) << 6) + (quad << 3);
    const f16x8_t a0 = load_h8(qh + qoff), a1 = load_h8(qh + qoff + 32);
    for (int c = t; c < NS_; c += 256) vnL[c] = vnG[(bh << 11) + c];
    const float KS = SCALE_ * LOG2E_;
    const int krow = lane >> 3, kblk = (lane & 7) ^ ((lane >> 3) & 7);
    const int vrow = lane >> 2, vblk = (lane & 3) ^ ((lane >> 3) & 3);
    const int e = m16 & 7;
    const int s00 = ((quad) ^ e) << 3, s01 = ((4 + quad) ^ e) << 3;
    const int vsw = (m16 >> 1) & 3;
    const f32x4_t z = {0.f, 0.f, 0.f, 0.f};
    f32x4_t xacc[4];
    #pragma unroll
    for (int nt = 0; nt < 4; nt++) xacc[nt] = z;
    float lr[4] = {0.f, 0.f, 0.f, 0.f};
    const size_t kbel = ((size_t)bh << 11) * HD_;
    _Float16* pw = pbuf[w];

    for (int kc = 0; kc < NS_; kc += 32) {
        __syncthreads();
        {
            const size_t ce = kbel + (size_t)kc * HD_;
            const size_t ve = ((size_t)(bh << 6) + (kc >> 5)) << 11;
            #pragma unroll
            for (int ci = 0; ci < 2; ci++) {
                const int call = (w << 1) + ci;
                if (call < 4) {
                    const _Float16* src = kh + ce + ((call * 8 + krow) << 6) + (kblk << 3);
                    gload_lds16(src, &Ksh[call << 9]);
                } else {
                    const int j = call - 4;
                    const _Float16* src = vT + ve + ((j * 16 + vrow) << 5) + (vblk << 3);
                    gload_lds16(src, &Vsh[j << 9]);
                }
            }
        }
        __syncthreads();
        const f16x8_t b00 = load_h8(&Ksh[(m16 << 6) + s00]);
        const f16x8_t b01 = load_h8(&Ksh[(m16 << 6) + s01]);
        const f16x8_t b10 = load_h8(&Ksh[((16 + m16) << 6) + s00]);
        const f16x8_t b11 = load_h8(&Ksh[((16 + m16) << 6) + s01]);
        f32x4_t c0 = MFMAH(a0, b00, z); c0 = MFMAH(a1, b01, c0);
        f32x4_t c1 = MFMAH(a0, b10, z); c1 = MFMAH(a1, b11, c1);
        const float vn0 = vnL[kc + m16], vn1 = vnL[kc + 16 + m16];
        #pragma unroll
        for (int r = 0; r < 4; r++) {
            const float p0 = exp2f(fmaf(c0[r], KS, vn0));
            const float p1 = exp2f(fmaf(c1[r], KS, vn1));
            lr[r] += p0 + p1;
            pw[(((quad << 2) + r) * 40) + m16]      = (_Float16)p0;
            pw[(((quad << 2) + r) * 40) + 16 + m16] = (_Float16)p1;
        }
        __threadfence_block();   // order P writes before P reads (same wave)
        const f16x8_t pa = load_h8(&pw[m16 * 40 + (quad << 3)]);
        #pragma unroll
        for (int nt = 0; nt < 4; nt++) {
            const f16x8_t vb = load_h8(&Vsh[((nt * 16 + m16) << 5) + ((quad ^ vsw) << 3)]);
            xacc[nt] = MFMAH(pa, vb, xacc[nt]);
        }
    }
    #pragma unroll
    for (int d = 1; d < 16; d <<= 1) {
        #pragma unroll
        for (int r = 0; r < 4; r++) lr[r] += __shfl_xor(lr[r], d, 64);
    }
    const int b = bh >> 3, h = bh & 7;
    #pragma unroll
    for (int r = 0; r < 4; r++) {
        const float li = 1.0f / lr[r];
        const int row = qbase + (quad << 2) + r;
        #pragma unroll
        for (int nt = 0; nt < 4; nt++)
            xbuf[(((size_t)b << 11) + row) * C_ + (h << 6) + (nt << 4) + m16] = xacc[nt][r] * li;
    }
}

// ---------------------------------------------------------------------------
extern "C" void kernel_launch(void* const* d_in, const int* in_sizes, int n_in,
                              void* d_out, int out_size, void* d_ws, size_t ws_size,
                              hipStream_t stream) {
    const float* q  = (const float*)d_in[0];
    const float* k  = (const float*)d_in[1];
    const float* v  = (const float*)d_in[2];
    const float* supp_valid = (const float*)d_in[3];
    const int*   supp_mask  = (const int*)d_in[4];
    const float* Wq = (const float*)d_in[5];
    const float* Wk = (const float*)d_in[6];
    const float* Wv = (const float*)d_in[7];
    const float* Wp = (const float*)d_in[8];
    float* out = (float*)d_out;

    char* p = (char*)d_ws;
    float* xbuf = (float*)p;           p += 8388608;   // [B,N,C] f32
    _Float16* qhi = (_Float16*)p;      p += 4194304;   // [B,H,N,HD] fp16 splits
    _Float16* qlo = (_Float16*)p;      p += 4194304;
    _Float16* khi = (_Float16*)p;      p += 4194304;
    _Float16* klo = (_Float16*)p;      p += 4194304;
    _Float16* vT  = (_Float16*)p;      p += 4194304;   // [B,H] chunk-tiled
    unsigned long long* q2kP = (unsigned long long*)p; p += 262144;
    unsigned long long* k2qP = (unsigned long long*)p; p += 262144;
    float* validNeg = (float*)p;       p += 131072;

    hipMemsetAsync(k2qP, 0, 262144, stream);   // colP needs zero init

    dim3 gG(64, 8), bG(256);
    gemm512<<<gG, bG, 0, stream>>>(q, Wq, nullptr, qhi, qlo, 0);
    gemm512<<<gG, bG, 0, stream>>>(k, Wk, nullptr, khi, klo, 0);
    gemm512<<<gG, bG, 0, stream>>>(v, Wv, nullptr, vT, nullptr, 2);

    argmax_mfma<<<512, bG, 0, stream>>>(qhi, qlo, khi, klo, q2kP, k2qP);

    resolve<<<128, 256, 0, stream>>>(q2kP, k2qP, supp_mask, supp_valid, validNeg);

    attn_pv<<<512, bG, 0, stream>>>(qhi, khi, vT, validNeg, xbuf);

    gemm512<<<gG, bG, 0, stream>>>(xbuf, Wp, out, nullptr, nullptr, 3);
}

// Round 5
// 270.404 us; speedup vs baseline: 2.3311x; 1.2879x over previous
//
#include <hip/hip_runtime.h>
#include <hip/hip_bf16.h>
#include <stdint.h>

#define H_ 8
#define NS_ 2048
#define C_ 512
#define HD_ 64
#define SCALE_ 0.125f
#define NEG_ -10000.0f
#define LOG2E_ 1.4426950408889634f
#define MFIX_ 4.0f

typedef _Float16 f16x8_t __attribute__((ext_vector_type(8)));
typedef _Float16 f16x4_t __attribute__((ext_vector_type(4)));
typedef float f32x4_t __attribute__((ext_vector_type(4)));

#define MFMAH(a, b, c) __builtin_amdgcn_mfma_f32_16x16x32_f16(a, b, c, 0, 0, 0)

__device__ inline f16x8_t load_h8(const _Float16* p) {
    return *reinterpret_cast<const f16x8_t*>(p);
}

// async global->LDS, 16B per lane; LDS dest = uniform base + lane*16
__device__ inline void gload_lds16(const void* g, void* l) {
    __builtin_amdgcn_global_load_lds(
        (const __attribute__((address_space(1))) unsigned int*)g,
        (__attribute__((address_space(3))) unsigned int*)l, 16, 0, 0);
}

__device__ inline unsigned orderF(float v) {
    unsigned u = __float_as_uint(v);
    return (u & 0x80000000u) ? ~u : (u | 0x80000000u);
}
__device__ inline unsigned long long packVR(float v, int idx) {
    return ((unsigned long long)orderF(v) << 32) | (unsigned)(~idx);
}
__device__ inline unsigned long long max64(unsigned long long a, unsigned long long b) {
    return a > b ? a : b;
}
__device__ inline unsigned long long shflx64(unsigned long long x, int m) {
    unsigned lo = (unsigned)x, hi = (unsigned)(x >> 32);
    lo = __shfl_xor(lo, m, 64);
    hi = __shfl_xor(hi, m, 64);
    return ((unsigned long long)hi << 32) | lo;
}

// ---------------------------------------------------------------------------
// K0: elementwise fp32 -> 2-way f16 split (hi = f16(x), lo = f16(x - hi))
// ---------------------------------------------------------------------------
__global__ __launch_bounds__(256) void split16(const float* __restrict__ src,
        _Float16* __restrict__ hi, _Float16* __restrict__ lo, int n4)
{
    const int i = blockIdx.x * 256 + threadIdx.x;
    if (i >= n4) return;
    const float4 v = reinterpret_cast<const float4*>(src)[i];
    f16x4_t hv, lv;
    hv[0] = (_Float16)v.x; hv[1] = (_Float16)v.y;
    hv[2] = (_Float16)v.z; hv[3] = (_Float16)v.w;
    lv[0] = (_Float16)(v.x - (float)hv[0]);
    lv[1] = (_Float16)(v.y - (float)hv[1]);
    lv[2] = (_Float16)(v.z - (float)hv[2]);
    lv[3] = (_Float16)(v.w - (float)hv[3]);
    reinterpret_cast<f16x4_t*>(hi)[i] = hv;
    reinterpret_cast<f16x4_t*>(lo)[i] = lv;
}

// ---------------------------------------------------------------------------
// K1: 3-term split-f16 MFMA GEMM: C[m,j] = sum_k A[m,k]*W[j,k], K=512.
// A = Ah+Al, W = Wh+Wl; terms hh + lh + hl (error ~2e-7 rel ~ fp32).
// Block = 4 waves, 128 rows x 64 cols; K in 8 chunks of 64; W chunk staged
// in LDS (dbuf, XOR swizzle, prefetch-after-barrier); A prefetched in regs.
// mode 0: Q/K hi/lo split out [bh][n][d]; mode 2: V tiled; mode 3: fp32 out.
// ---------------------------------------------------------------------------
__global__ __launch_bounds__(256) void gemm_mfma(
        const _Float16* __restrict__ Ah, const _Float16* __restrict__ Al,
        const _Float16* __restrict__ Wh, const _Float16* __restrict__ Wl,
        float* __restrict__ outF, _Float16* __restrict__ o1,
        _Float16* __restrict__ o2, int mode)
{
    __shared__ __attribute__((aligned(16))) _Float16 Wsh[2][2][4096];  // 32 KB
    const int t = threadIdx.x, w = t >> 6, lane = t & 63;
    const int m16 = lane & 15, quad = lane >> 4;
    const int bm = blockIdx.x << 7, bn = blockIdx.y << 6;
    const int r0 = bm + (w << 5) + m16, r1 = r0 + 16;
    const int krow = lane >> 3, kblk = (lane & 7) ^ (krow & 7);
    const int e = m16 & 7;
    const int s00 = (quad ^ e) << 3, s01 = ((4 + quad) ^ e) << 3;
    const f32x4_t z = {0.f, 0.f, 0.f, 0.f};
    f32x4_t acc[2][4];
    #pragma unroll
    for (int rs = 0; rs < 2; rs++)
        #pragma unroll
        for (int tl = 0; tl < 4; tl++) acc[rs][tl] = z;

    auto stageW = [&](int buf, int kc) {
        #pragma unroll
        for (int ci = 0; ci < 4; ci++) {
            const int pp = (w << 2) + ci;
            const int s = pp >> 3, pj = pp & 7;
            const _Float16* src = (s ? Wl : Wh)
                + (size_t)(bn + (pj << 3) + krow) * C_ + kc + (kblk << 3);
            gload_lds16(src, &Wsh[buf][s][pj << 9]);
        }
    };
    auto loadA = [&](int kc, f16x8_t* d) {
        const _Float16* p0h = Ah + (size_t)r0 * C_ + kc + (quad << 3);
        const _Float16* p0l = Al + (size_t)r0 * C_ + kc + (quad << 3);
        const _Float16* p1h = Ah + (size_t)r1 * C_ + kc + (quad << 3);
        const _Float16* p1l = Al + (size_t)r1 * C_ + kc + (quad << 3);
        d[0] = load_h8(p0h); d[1] = load_h8(p0h + 32);
        d[2] = load_h8(p0l); d[3] = load_h8(p0l + 32);
        d[4] = load_h8(p1h); d[5] = load_h8(p1h + 32);
        d[6] = load_h8(p1l); d[7] = load_h8(p1l + 32);
    };

    f16x8_t cA[8], nA[8];
    stageW(0, 0);
    loadA(0, cA);
    for (int ch = 0; ch < 8; ch++) {
        __syncthreads();
        if (ch + 1 < 8) {
            stageW((ch + 1) & 1, (ch + 1) << 6);
            loadA((ch + 1) << 6, nA);
        }
        const _Float16* W0 = Wsh[ch & 1][0];
        const _Float16* W1 = Wsh[ch & 1][1];
        #pragma unroll
        for (int tl = 0; tl < 4; tl++) {
            const int j64 = ((tl << 4) + m16) << 6;
            const f16x8_t bh0 = load_h8(&W0[j64 + s00]);
            const f16x8_t bh1 = load_h8(&W0[j64 + s01]);
            const f16x8_t bl0 = load_h8(&W1[j64 + s00]);
            const f16x8_t bl1 = load_h8(&W1[j64 + s01]);
            f32x4_t c0 = acc[0][tl];
            c0 = MFMAH(cA[0], bh0, c0); c0 = MFMAH(cA[1], bh1, c0);
            c0 = MFMAH(cA[2], bh0, c0); c0 = MFMAH(cA[3], bh1, c0);
            c0 = MFMAH(cA[0], bl0, c0); c0 = MFMAH(cA[1], bl1, c0);
            acc[0][tl] = c0;
            f32x4_t c1 = acc[1][tl];
            c1 = MFMAH(cA[4], bh0, c1); c1 = MFMAH(cA[5], bh1, c1);
            c1 = MFMAH(cA[6], bh0, c1); c1 = MFMAH(cA[7], bh1, c1);
            c1 = MFMAH(cA[4], bl0, c1); c1 = MFMAH(cA[5], bl1, c1);
            acc[1][tl] = c1;
        }
        #pragma unroll
        for (int i = 0; i < 8; i++) cA[i] = nA[i];
    }
    const int by = blockIdx.y;
    #pragma unroll
    for (int rs = 0; rs < 2; rs++) {
        #pragma unroll
        for (int tl = 0; tl < 4; tl++) {
            #pragma unroll
            for (int r = 0; r < 4; r++) {
                const int gr = bm + (w << 5) + (rs << 4) + (quad << 2) + r;
                const int gj = bn + (tl << 4) + m16;
                const float val = acc[rs][tl][r];
                if (mode == 3) {
                    outF[(size_t)gr * C_ + gj] = val;
                } else {
                    const int b = gr >> 11, n = gr & 2047;
                    const int d = (tl << 4) + m16;
                    const int bh = (b << 3) + by;
                    if (mode == 2) {
                        o1[(((size_t)((bh << 6) + (n >> 5)) << 6) + d) * 32 + (n & 31)] = (_Float16)val;
                    } else {
                        const size_t idx = ((((size_t)bh << 11) + n) << 6) + d;
                        const _Float16 hh = (_Float16)val;
                        o1[idx] = hh;
                        o2[idx] = (_Float16)(val - (float)hh);
                    }
                }
            }
        }
    }
}

// ---------------------------------------------------------------------------
// K2: MFMA split-f16 argmax. 32 rows/wave (2 rowsets share B frags), 64-key
// chunks, dbuf LDS staging w/ prefetch-after-barrier, key-space split in 2.
// Row argmax -> global atomicMax (packed u64, first-index ties); col argmax
// -> in-lane 8-row reduce, quad butterfly, LDS atomicMax, block merge.
// XCD-pinned: bh pair {2x,2x+1} on XCD x.
// ---------------------------------------------------------------------------
__global__ __launch_bounds__(256) void argmax_mfma(
        const _Float16* __restrict__ qhi, const _Float16* __restrict__ qlo,
        const _Float16* __restrict__ khi, const _Float16* __restrict__ klo,
        unsigned long long* __restrict__ rowP, unsigned long long* __restrict__ colP)
{
    __shared__ __attribute__((aligned(16))) _Float16 Ksh[2][2][4096];  // 32 KB
    __shared__ unsigned long long colbest[1024];                       // 8 KB
    const int bx = blockIdx.x;
    const int bh = ((bx & 7) << 1) | (bx >> 8);
    const int rt = (bx >> 3) & 15;
    const int ks = (bx >> 7) & 1;
    const int t = threadIdx.x, w = t >> 6, lane = t & 63;
    const int m16 = lane & 15, quad = lane >> 4;
    const int wrow = (rt << 7) + (w << 5);
    const size_t qoff0 = ((((size_t)bh << 11) + wrow + m16) << 6) + (quad << 3);
    const size_t qoff1 = qoff0 + 1024;
    const f16x8_t a00h = load_h8(qhi + qoff0), a01h = load_h8(qhi + qoff0 + 32);
    const f16x8_t a00l = load_h8(qlo + qoff0), a01l = load_h8(qlo + qoff0 + 32);
    const f16x8_t a10h = load_h8(qhi + qoff1), a11h = load_h8(qhi + qoff1 + 32);
    const f16x8_t a10l = load_h8(qlo + qoff1), a11l = load_h8(qlo + qoff1 + 32);
    for (int c = t; c < 1024; c += 256) colbest[c] = 0;
    const int krow = lane >> 3, kblk = (lane & 7) ^ (krow & 7);
    const int e = m16 & 7;
    const int s00 = (quad ^ e) << 3, s01 = ((4 + quad) ^ e) << 3;
    const size_t kbase = (((size_t)bh << 11) + (ks << 10)) << 6;
    float bv0[4] = {-3.4e38f, -3.4e38f, -3.4e38f, -3.4e38f};
    float bv1[4] = {-3.4e38f, -3.4e38f, -3.4e38f, -3.4e38f};
    int bc0[4] = {0, 0, 0, 0}, bc1[4] = {0, 0, 0, 0};
    const f32x4_t z = {0.f, 0.f, 0.f, 0.f};

    auto stage = [&](int buf, int cidx) {
        const size_t ce = kbase + ((size_t)cidx << 12);
        #pragma unroll
        for (int ci = 0; ci < 4; ci++) {
            const int pp = (w << 2) + ci;
            const int s = pp >> 3, pj = pp & 7;
            const _Float16* src = (s ? klo : khi) + ce + (((pj << 3) + krow) << 6) + (kblk << 3);
            gload_lds16(src, &Ksh[buf][s][pj << 9]);
        }
    };

    stage(0, 0);
    for (int ch = 0; ch < 16; ch++) {
        __syncthreads();
        if (ch + 1 < 16) stage((ch + 1) & 1, ch + 1);
        const _Float16* K0 = Ksh[ch & 1][0];
        const _Float16* K1 = Ksh[ch & 1][1];
        const int kc0 = (ks << 10) + (ch << 6);
        #pragma unroll
        for (int tl = 0; tl < 4; tl++) {
            const int j64 = ((tl << 4) + m16) << 6;
            const f16x8_t bh0 = load_h8(&K0[j64 + s00]);
            const f16x8_t bh1 = load_h8(&K0[j64 + s01]);
            const f16x8_t bl0 = load_h8(&K1[j64 + s00]);
            const f16x8_t bl1 = load_h8(&K1[j64 + s01]);
            f32x4_t c0 = MFMAH(a00h, bh0, z);
            c0 = MFMAH(a01h, bh1, c0);
            c0 = MFMAH(a00l, bh0, c0); c0 = MFMAH(a01l, bh1, c0);
            c0 = MFMAH(a00h, bl0, c0); c0 = MFMAH(a01h, bl1, c0);
            f32x4_t c1 = MFMAH(a10h, bh0, z);
            c1 = MFMAH(a11h, bh1, c1);
            c1 = MFMAH(a10l, bh0, c1); c1 = MFMAH(a11l, bh1, c1);
            c1 = MFMAH(a10h, bl0, c1); c1 = MFMAH(a11h, bl1, c1);
            const int gc = kc0 + (tl << 4) + m16;
            #pragma unroll
            for (int r = 0; r < 4; r++) {
                if (c0[r] > bv0[r]) { bv0[r] = c0[r]; bc0[r] = gc; }
                if (c1[r] > bv1[r]) { bv1[r] = c1[r]; bc1[r] = gc; }
            }
            // col argmax: in-lane over 8 rows (rowset0 first -> smallest row)
            float v = c0[0]; int ri = (quad << 2);
            if (c0[1] > v) { v = c0[1]; ri = (quad << 2) + 1; }
            if (c0[2] > v) { v = c0[2]; ri = (quad << 2) + 2; }
            if (c0[3] > v) { v = c0[3]; ri = (quad << 2) + 3; }
            if (c1[0] > v) { v = c1[0]; ri = 16 + (quad << 2); }
            if (c1[1] > v) { v = c1[1]; ri = 16 + (quad << 2) + 1; }
            if (c1[2] > v) { v = c1[2]; ri = 16 + (quad << 2) + 2; }
            if (c1[3] > v) { v = c1[3]; ri = 16 + (quad << 2) + 3; }
            unsigned long long pk = packVR(v, wrow + ri);
            pk = max64(pk, shflx64(pk, 16));
            pk = max64(pk, shflx64(pk, 32));
            if (quad == 0) atomicMax(&colbest[(ch << 6) + (tl << 4) + m16], pk);
        }
    }
    #pragma unroll
    for (int r = 0; r < 4; r++) {
        unsigned long long p0 = packVR(bv0[r], bc0[r]);
        p0 = max64(p0, shflx64(p0, 1)); p0 = max64(p0, shflx64(p0, 2));
        p0 = max64(p0, shflx64(p0, 4)); p0 = max64(p0, shflx64(p0, 8));
        if (m16 == 0)
            atomicMax(rowP + ((size_t)bh << 11) + wrow + (quad << 2) + r, p0);
        unsigned long long p1 = packVR(bv1[r], bc1[r]);
        p1 = max64(p1, shflx64(p1, 1)); p1 = max64(p1, shflx64(p1, 2));
        p1 = max64(p1, shflx64(p1, 4)); p1 = max64(p1, shflx64(p1, 8));
        if (m16 == 0)
            atomicMax(rowP + ((size_t)bh << 11) + wrow + 16 + (quad << 2) + r, p1);
    }
    __syncthreads();
    for (int c = t; c < 1024; c += 256)
        atomicMax(colP + ((size_t)bh << 11) + (ks << 10) + c, colbest[c]);
}

// ---------------------------------------------------------------------------
// K3: cycle-consistency resolve -> vn[b,h,j] = valid*NEG*LOG2E - MFIX
// ---------------------------------------------------------------------------
__global__ __launch_bounds__(256) void resolve(const unsigned long long* __restrict__ q2kP,
        const unsigned long long* __restrict__ k2qP, const int* __restrict__ supp_mask,
        const float* __restrict__ supp_valid, float* __restrict__ vn)
{
    const int t = blockIdx.x * 256 + threadIdx.x;      // 32768 = B*H*NS
    const int bh = t >> 11, j = t & 2047, b = bh >> 3;
    const unsigned k2q = 0xFFFFFFFFu - (unsigned)(k2qP[t] & 0xFFFFFFFFull);
    const unsigned rm  = 0xFFFFFFFFu - (unsigned)(q2kP[(bh << 11) + k2q] & 0xFFFFFFFFull);
    const int asso = supp_mask[(b << 11) + j] == supp_mask[(b << 11) + (int)rm];
    const float valid = asso ? supp_valid[(b << 11) + j] : 1.0f;
    vn[t] = fmaf(valid, NEG_ * LOG2E_, -MFIX_);
}

// ---------------------------------------------------------------------------
// K4: fused attention, dbuf staging (1 barrier/chunk). p = exp2(s + vn)
// (fixed max), l in-pass; P -> per-wave LDS strip -> PV MFMA; epilogue
// writes x as f16 hi/lo splits for the final gemm_mfma. XCD-pinned.
// ---------------------------------------------------------------------------
__global__ __launch_bounds__(256) void attn_pv(
        const _Float16* __restrict__ qh, const _Float16* __restrict__ kh,
        const _Float16* __restrict__ vT, const float* __restrict__ vnG,
        _Float16* __restrict__ xh, _Float16* __restrict__ xl)
{
    __shared__ __attribute__((aligned(16))) _Float16 Ksh[2][2048];   // 8 KB
    __shared__ __attribute__((aligned(16))) _Float16 Vsh[2][2048];   // 8 KB
    __shared__ float vnL[NS_];                                       // 8 KB
    __shared__ __attribute__((aligned(16))) _Float16 pbuf[4][16*40]; // 5 KB
    const int bx = blockIdx.x;
    const int bh = ((bx & 7) << 1) | ((bx >> 3) >> 5);
    const int rt = (bx >> 3) & 31;
    const int t = threadIdx.x, w = t >> 6, lane = t & 63;
    const int m16 = lane & 15, quad = lane >> 4;
    const int qbase = (rt << 6) + (w << 4);
    const size_t qoff = ((((size_t)bh << 11) + qbase + m16) << 6) + (quad << 3);
    const f16x8_t a0 = load_h8(qh + qoff), a1 = load_h8(qh + qoff + 32);
    for (int c = t; c < NS_; c += 256) vnL[c] = vnG[(bh << 11) + c];
    const float KS = SCALE_ * LOG2E_;
    const int krow = lane >> 3, kblk = (lane & 7) ^ ((lane >> 3) & 7);
    const int vrow = lane >> 2, vblk = (lane & 3) ^ ((lane >> 3) & 3);
    const int e = m16 & 7;
    const int s00 = (quad ^ e) << 3, s01 = ((4 + quad) ^ e) << 3;
    const int vsw = (m16 >> 1) & 3;
    const f32x4_t z = {0.f, 0.f, 0.f, 0.f};
    f32x4_t xacc[4];
    #pragma unroll
    for (int nt = 0; nt < 4; nt++) xacc[nt] = z;
    float lr[4] = {0.f, 0.f, 0.f, 0.f};
    const size_t kbel = ((size_t)bh << 11) * HD_;
    _Float16* pw = pbuf[w];

    auto stage = [&](int buf, int kc) {
        const size_t ce = kbel + (size_t)kc * HD_;
        const size_t ve = ((size_t)(bh << 6) + (kc >> 5)) << 11;
        #pragma unroll
        for (int ci = 0; ci < 2; ci++) {
            const int call = (w << 1) + ci;
            if (call < 4) {
                const _Float16* src = kh + ce + ((call * 8 + krow) << 6) + (kblk << 3);
                gload_lds16(src, &Ksh[buf][call << 9]);
            } else {
                const int j = call - 4;
                const _Float16* src = vT + ve + ((j * 16 + vrow) << 5) + (vblk << 3);
                gload_lds16(src, &Vsh[buf][j << 9]);
            }
        }
    };

    stage(0, 0);
    for (int ch = 0; ch < 64; ch++) {
        const int kc = ch << 5;
        __syncthreads();
        if (ch + 1 < 64) stage((ch + 1) & 1, kc + 32);
        const _Float16* K = Ksh[ch & 1];
        const _Float16* V = Vsh[ch & 1];
        const f16x8_t b00 = load_h8(&K[(m16 << 6) + s00]);
        const f16x8_t b01 = load_h8(&K[(m16 << 6) + s01]);
        const f16x8_t b10 = load_h8(&K[((16 + m16) << 6) + s00]);
        const f16x8_t b11 = load_h8(&K[((16 + m16) << 6) + s01]);
        f32x4_t c0 = MFMAH(a0, b00, z); c0 = MFMAH(a1, b01, c0);
        f32x4_t c1 = MFMAH(a0, b10, z); c1 = MFMAH(a1, b11, c1);
        const float vn0 = vnL[kc + m16], vn1 = vnL[kc + 16 + m16];
        #pragma unroll
        for (int r = 0; r < 4; r++) {
            const float p0 = exp2f(fmaf(c0[r], KS, vn0));
            const float p1 = exp2f(fmaf(c1[r], KS, vn1));
            lr[r] += p0 + p1;
            pw[(((quad << 2) + r) * 40) + m16]      = (_Float16)p0;
            pw[(((quad << 2) + r) * 40) + 16 + m16] = (_Float16)p1;
        }
        __threadfence_block();   // order P writes before P reads (same wave)
        const f16x8_t pa = load_h8(&pw[m16 * 40 + (quad << 3)]);
        #pragma unroll
        for (int nt = 0; nt < 4; nt++) {
            const f16x8_t vb = load_h8(&V[((nt * 16 + m16) << 5) + ((quad ^ vsw) << 3)]);
            xacc[nt] = MFMAH(pa, vb, xacc[nt]);
        }
    }
    #pragma unroll
    for (int d = 1; d < 16; d <<= 1) {
        #pragma unroll
        for (int r = 0; r < 4; r++) lr[r] += __shfl_xor(lr[r], d, 64);
    }
    const int b = bh >> 3, h = bh & 7;
    #pragma unroll
    for (int r = 0; r < 4; r++) {
        const float li = 1.0f / lr[r];
        const int row = qbase + (quad << 2) + r;
        #pragma unroll
        for (int nt = 0; nt < 4; nt++) {
            const float val = xacc[nt][r] * li;
            const size_t idx = (((size_t)b << 11) + row) * C_ + (h << 6) + (nt << 4) + m16;
            const _Float16 hh = (_Float16)val;
            xh[idx] = hh;
            xl[idx] = (_Float16)(val - (float)hh);
        }
    }
}

// ---------------------------------------------------------------------------
extern "C" void kernel_launch(void* const* d_in, const int* in_sizes, int n_in,
                              void* d_out, int out_size, void* d_ws, size_t ws_size,
                              hipStream_t stream) {
    const float* q  = (const float*)d_in[0];
    const float* k  = (const float*)d_in[1];
    const float* v  = (const float*)d_in[2];
    const float* supp_valid = (const float*)d_in[3];
    const int*   supp_mask  = (const int*)d_in[4];
    const float* Wq = (const float*)d_in[5];
    const float* Wk = (const float*)d_in[6];
    const float* Wv = (const float*)d_in[7];
    const float* Wp = (const float*)d_in[8];
    float* out = (float*)d_out;

    char* p = (char*)d_ws;
    _Float16* qhi = (_Float16*)p;      p += 4194304;   // [bh][n][d] f16 splits
    _Float16* qlo = (_Float16*)p;      p += 4194304;
    _Float16* khi = (_Float16*)p;      p += 4194304;
    _Float16* klo = (_Float16*)p;      p += 4194304;
    _Float16* vT  = (_Float16*)p;      p += 4194304;   // [bh] chunk-tiled
    _Float16* inH = (_Float16*)p;      p += 4194304;   // reused: q/k/v splits, then x splits
    _Float16* inL = (_Float16*)p;      p += 4194304;
    _Float16* wH  = (_Float16*)p;      p += 524288;    // reused per-W
    _Float16* wL  = (_Float16*)p;      p += 524288;
    unsigned long long* q2kP = (unsigned long long*)p; p += 262144;
    unsigned long long* k2qP = (unsigned long long*)p; p += 262144;
    float* validNeg = (float*)p;       p += 131072;

    hipMemsetAsync(q2kP, 0, 524288, stream);           // rowP + colP zero init

    dim3 bG(256), gG(32, 8);
    split16<<<2048, bG, 0, stream>>>(q, inH, inL, 524288);
    split16<<<256, bG, 0, stream>>>(Wq, wH, wL, 65536);
    gemm_mfma<<<gG, bG, 0, stream>>>(inH, inL, wH, wL, nullptr, qhi, qlo, 0);
    split16<<<2048, bG, 0, stream>>>(k, inH, inL, 524288);
    split16<<<256, bG, 0, stream>>>(Wk, wH, wL, 65536);
    gemm_mfma<<<gG, bG, 0, stream>>>(inH, inL, wH, wL, nullptr, khi, klo, 0);
    split16<<<2048, bG, 0, stream>>>(v, inH, inL, 524288);
    split16<<<256, bG, 0, stream>>>(Wv, wH, wL, 65536);
    gemm_mfma<<<gG, bG, 0, stream>>>(inH, inL, wH, wL, nullptr, vT, nullptr, 2);

    argmax_mfma<<<512, bG, 0, stream>>>(qhi, qlo, khi, klo, q2kP, k2qP);

    resolve<<<128, bG, 0, stream>>>(q2kP, k2qP, supp_mask, supp_valid, validNeg);

    attn_pv<<<512, bG, 0, stream>>>(qhi, khi, vT, validNeg, inH, inL);

    split16<<<256, bG, 0, stream>>>(Wp, wH, wL, 65536);
    gemm_mfma<<<gG, bG, 0, stream>>>(inH, inL, wH, wL, out, nullptr, nullptr, 3);
}

// Round 6
// 234.077 us; speedup vs baseline: 2.6929x; 1.1552x over previous
//
#include <hip/hip_runtime.h>
#include <hip/hip_bf16.h>
#include <stdint.h>

#define H_ 8
#define NS_ 2048
#define C_ 512
#define HD_ 64
#define SCALE_ 0.125f
#define NEG_ -10000.0f
#define LOG2E_ 1.4426950408889634f
#define MFIX_ 4.0f

typedef _Float16 f16x8_t __attribute__((ext_vector_type(8)));
typedef _Float16 f16x4_t __attribute__((ext_vector_type(4)));
typedef float f32x4_t __attribute__((ext_vector_type(4)));

#define MFMAH(a, b, c) __builtin_amdgcn_mfma_f32_16x16x32_f16(a, b, c, 0, 0, 0)

__device__ inline f16x8_t load_h8(const _Float16* p) {
    return *reinterpret_cast<const f16x8_t*>(p);
}

// async global->LDS, 16B per lane; LDS dest = uniform base + lane*16
__device__ inline void gload_lds16(const void* g, void* l) {
    __builtin_amdgcn_global_load_lds(
        (const __attribute__((address_space(1))) unsigned int*)g,
        (__attribute__((address_space(3))) unsigned int*)l, 16, 0, 0);
}

__device__ inline unsigned orderF(float v) {
    unsigned u = __float_as_uint(v);
    return (u & 0x80000000u) ? ~u : (u | 0x80000000u);
}
__device__ inline unsigned long long packVR(float v, int idx) {
    return ((unsigned long long)orderF(v) << 32) | (unsigned)(~idx);
}
__device__ inline unsigned long long max64(unsigned long long a, unsigned long long b) {
    return a > b ? a : b;
}
__device__ inline unsigned long long shflx64(unsigned long long x, int m) {
    unsigned lo = (unsigned)x, hi = (unsigned)(x >> 32);
    lo = __shfl_xor(lo, m, 64);
    hi = __shfl_xor(hi, m, 64);
    return ((unsigned long long)hi << 32) | lo;
}

// ---------------------------------------------------------------------------
// K0: all four 512x512 weights -> f16 hi/lo splits in one launch.
// grid (256, 4): y selects the weight; slot y in wH/wL.
// ---------------------------------------------------------------------------
__global__ __launch_bounds__(256) void wsplit4(
        const float* __restrict__ w0, const float* __restrict__ w1,
        const float* __restrict__ w2, const float* __restrict__ w3,
        _Float16* __restrict__ hi, _Float16* __restrict__ lo)
{
    const int i = blockIdx.x * 256 + threadIdx.x;            // 65536 float4 / W
    const int y = blockIdx.y;
    const float* src = (y == 0) ? w0 : (y == 1) ? w1 : (y == 2) ? w2 : w3;
    const float4 v = reinterpret_cast<const float4*>(src)[i];
    f16x4_t hv, lv;
    hv[0] = (_Float16)v.x; hv[1] = (_Float16)v.y;
    hv[2] = (_Float16)v.z; hv[3] = (_Float16)v.w;
    lv[0] = (_Float16)(v.x - (float)hv[0]);
    lv[1] = (_Float16)(v.y - (float)hv[1]);
    lv[2] = (_Float16)(v.z - (float)hv[2]);
    lv[3] = (_Float16)(v.w - (float)hv[3]);
    const size_t o = ((size_t)y << 16) + i;                  // float4 index
    reinterpret_cast<f16x4_t*>(hi)[o] = hv;
    reinterpret_cast<f16x4_t*>(lo)[o] = lv;
}

// ---------------------------------------------------------------------------
// K1: projection GEMM (all three in one launch, grid.z selects q/k/v).
// C[m,j] = sum_k A[m,k]*W[j,k], K=512; A fp32 split to f16 hi/lo on the fly;
// 3-term split MFMA (hh + lh + hl, ~fp32 accuracy). 128x64 tile, W chunk in
// dbuf LDS (XOR swizzle, prefetch-after-barrier).
// z<2: hi/lo split out [bh][n][d];  z==2: V tiled [bh][key>>5][d][key&31].
// ---------------------------------------------------------------------------
__global__ __launch_bounds__(256) void proj_gemm(
        const float* __restrict__ qin, const float* __restrict__ kin,
        const float* __restrict__ vin,
        const _Float16* __restrict__ wHall, const _Float16* __restrict__ wLall,
        _Float16* __restrict__ qhi, _Float16* __restrict__ qlo,
        _Float16* __restrict__ khi, _Float16* __restrict__ klo,
        _Float16* __restrict__ vT)
{
    __shared__ __attribute__((aligned(16))) _Float16 Wsh[2][2][4096];  // 32 KB
    const int zz = blockIdx.z;
    const float* A32 = (zz == 0) ? qin : (zz == 1) ? kin : vin;
    const _Float16* Wh = wHall + ((size_t)zz << 18);
    const _Float16* Wl = wLall + ((size_t)zz << 18);
    const int t = threadIdx.x, w = t >> 6, lane = t & 63;
    const int m16 = lane & 15, quad = lane >> 4;
    const int bm = blockIdx.x << 7, bn = blockIdx.y << 6;
    const int r0 = bm + (w << 5) + m16, r1 = r0 + 16;
    const int krow = lane >> 3, kblk = (lane & 7) ^ (krow & 7);
    const int e = m16 & 7;
    const int s00 = (quad ^ e) << 3, s01 = ((4 + quad) ^ e) << 3;
    const f32x4_t z = {0.f, 0.f, 0.f, 0.f};
    f32x4_t acc[2][4];
    #pragma unroll
    for (int rs = 0; rs < 2; rs++)
        #pragma unroll
        for (int tl = 0; tl < 4; tl++) acc[rs][tl] = z;

    auto stageW = [&](int buf, int kc) {
        #pragma unroll
        for (int ci = 0; ci < 4; ci++) {
            const int pp = (w << 2) + ci;
            const int s = pp >> 3, pj = pp & 7;
            const _Float16* src = (s ? Wl : Wh)
                + (size_t)(bn + (pj << 3) + krow) * C_ + kc + (kblk << 3);
            gload_lds16(src, &Wsh[buf][s][pj << 9]);
        }
    };
    auto loadA = [&](int kc, f16x8_t* d) {
        #pragma unroll
        for (int rs = 0; rs < 2; rs++) {
            const float* pr = A32 + (size_t)(rs ? r1 : r0) * C_ + kc + (quad << 3);
            #pragma unroll
            for (int seg = 0; seg < 2; seg++) {
                f16x8_t hv, lv;
                #pragma unroll
                for (int i = 0; i < 8; i++) {
                    const float x = pr[seg * 32 + i];
                    const _Float16 hh = (_Float16)x;
                    hv[i] = hh;
                    lv[i] = (_Float16)(x - (float)hh);
                }
                d[rs * 4 + seg] = hv;
                d[rs * 4 + seg + 2] = lv;
            }
        }
    };

    f16x8_t cA[8], nA[8];
    stageW(0, 0);
    loadA(0, cA);
    for (int ch = 0; ch < 8; ch++) {
        __syncthreads();
        if (ch + 1 < 8) {
            stageW((ch + 1) & 1, (ch + 1) << 6);
            loadA((ch + 1) << 6, nA);
        }
        const _Float16* W0 = Wsh[ch & 1][0];
        const _Float16* W1 = Wsh[ch & 1][1];
        #pragma unroll
        for (int tl = 0; tl < 4; tl++) {
            const int j64 = ((tl << 4) + m16) << 6;
            const f16x8_t bh0 = load_h8(&W0[j64 + s00]);
            const f16x8_t bh1 = load_h8(&W0[j64 + s01]);
            const f16x8_t bl0 = load_h8(&W1[j64 + s00]);
            const f16x8_t bl1 = load_h8(&W1[j64 + s01]);
            f32x4_t c0 = acc[0][tl];
            c0 = MFMAH(cA[0], bh0, c0); c0 = MFMAH(cA[1], bh1, c0);
            c0 = MFMAH(cA[2], bh0, c0); c0 = MFMAH(cA[3], bh1, c0);
            c0 = MFMAH(cA[0], bl0, c0); c0 = MFMAH(cA[1], bl1, c0);
            acc[0][tl] = c0;
            f32x4_t c1 = acc[1][tl];
            c1 = MFMAH(cA[4], bh0, c1); c1 = MFMAH(cA[5], bh1, c1);
            c1 = MFMAH(cA[6], bh0, c1); c1 = MFMAH(cA[7], bh1, c1);
            c1 = MFMAH(cA[4], bl0, c1); c1 = MFMAH(cA[5], bl1, c1);
            acc[1][tl] = c1;
        }
        #pragma unroll
        for (int i = 0; i < 8; i++) cA[i] = nA[i];
    }
    const int by = blockIdx.y;
    _Float16* o1 = (zz == 0) ? qhi : khi;
    _Float16* o2 = (zz == 0) ? qlo : klo;
    #pragma unroll
    for (int rs = 0; rs < 2; rs++) {
        #pragma unroll
        for (int tl = 0; tl < 4; tl++) {
            #pragma unroll
            for (int r = 0; r < 4; r++) {
                const int gr = bm + (w << 5) + (rs << 4) + (quad << 2) + r;
                const float val = acc[rs][tl][r];
                const int b = gr >> 11, n = gr & 2047;
                const int d = (tl << 4) + m16;
                const int bh = (b << 3) + by;
                if (zz == 2) {
                    vT[(((size_t)((bh << 6) + (n >> 5)) << 6) + d) * 32 + (n & 31)] = (_Float16)val;
                } else {
                    const size_t idx = ((((size_t)bh << 11) + n) << 6) + d;
                    const _Float16 hh = (_Float16)val;
                    o1[idx] = hh;
                    o2[idx] = (_Float16)(val - (float)hh);
                }
            }
        }
    }
}

// ---------------------------------------------------------------------------
// K2: MFMA split-f16 argmax. 32 rows/wave, 64-key chunks, dbuf LDS staging,
// key-space split in 2. Row argmax -> global atomicMax (packed u64,
// first-index ties); col argmax -> in-lane reduce, quad butterfly, LDS
// atomicMax, block merge. XCD-pinned: bh pair {2x,2x+1} on XCD x.
// ---------------------------------------------------------------------------
__global__ __launch_bounds__(256) void argmax_mfma(
        const _Float16* __restrict__ qhi, const _Float16* __restrict__ qlo,
        const _Float16* __restrict__ khi, const _Float16* __restrict__ klo,
        unsigned long long* __restrict__ rowP, unsigned long long* __restrict__ colP)
{
    __shared__ __attribute__((aligned(16))) _Float16 Ksh[2][2][4096];  // 32 KB
    __shared__ unsigned long long colbest[1024];                       // 8 KB
    const int bx = blockIdx.x;
    const int bh = ((bx & 7) << 1) | (bx >> 8);
    const int rt = (bx >> 3) & 15;
    const int ks = (bx >> 7) & 1;
    const int t = threadIdx.x, w = t >> 6, lane = t & 63;
    const int m16 = lane & 15, quad = lane >> 4;
    const int wrow = (rt << 7) + (w << 5);
    const size_t qoff0 = ((((size_t)bh << 11) + wrow + m16) << 6) + (quad << 3);
    const size_t qoff1 = qoff0 + 1024;
    const f16x8_t a00h = load_h8(qhi + qoff0), a01h = load_h8(qhi + qoff0 + 32);
    const f16x8_t a00l = load_h8(qlo + qoff0), a01l = load_h8(qlo + qoff0 + 32);
    const f16x8_t a10h = load_h8(qhi + qoff1), a11h = load_h8(qhi + qoff1 + 32);
    const f16x8_t a10l = load_h8(qlo + qoff1), a11l = load_h8(qlo + qoff1 + 32);
    for (int c = t; c < 1024; c += 256) colbest[c] = 0;
    const int krow = lane >> 3, kblk = (lane & 7) ^ (krow & 7);
    const int e = m16 & 7;
    const int s00 = (quad ^ e) << 3, s01 = ((4 + quad) ^ e) << 3;
    const size_t kbase = (((size_t)bh << 11) + (ks << 10)) << 6;
    float bv0[4] = {-3.4e38f, -3.4e38f, -3.4e38f, -3.4e38f};
    float bv1[4] = {-3.4e38f, -3.4e38f, -3.4e38f, -3.4e38f};
    int bc0[4] = {0, 0, 0, 0}, bc1[4] = {0, 0, 0, 0};
    const f32x4_t z = {0.f, 0.f, 0.f, 0.f};

    auto stage = [&](int buf, int cidx) {
        const size_t ce = kbase + ((size_t)cidx << 12);
        #pragma unroll
        for (int ci = 0; ci < 4; ci++) {
            const int pp = (w << 2) + ci;
            const int s = pp >> 3, pj = pp & 7;
            const _Float16* src = (s ? klo : khi) + ce + (((pj << 3) + krow) << 6) + (kblk << 3);
            gload_lds16(src, &Ksh[buf][s][pj << 9]);
        }
    };

    stage(0, 0);
    for (int ch = 0; ch < 16; ch++) {
        __syncthreads();
        if (ch + 1 < 16) stage((ch + 1) & 1, ch + 1);
        const _Float16* K0 = Ksh[ch & 1][0];
        const _Float16* K1 = Ksh[ch & 1][1];
        const int kc0 = (ks << 10) + (ch << 6);
        #pragma unroll
        for (int tl = 0; tl < 4; tl++) {
            const int j64 = ((tl << 4) + m16) << 6;
            const f16x8_t bh0 = load_h8(&K0[j64 + s00]);
            const f16x8_t bh1 = load_h8(&K0[j64 + s01]);
            const f16x8_t bl0 = load_h8(&K1[j64 + s00]);
            const f16x8_t bl1 = load_h8(&K1[j64 + s01]);
            f32x4_t c0 = MFMAH(a00h, bh0, z);
            c0 = MFMAH(a01h, bh1, c0);
            c0 = MFMAH(a00l, bh0, c0); c0 = MFMAH(a01l, bh1, c0);
            c0 = MFMAH(a00h, bl0, c0); c0 = MFMAH(a01h, bl1, c0);
            f32x4_t c1 = MFMAH(a10h, bh0, z);
            c1 = MFMAH(a11h, bh1, c1);
            c1 = MFMAH(a10l, bh0, c1); c1 = MFMAH(a11l, bh1, c1);
            c1 = MFMAH(a10h, bl0, c1); c1 = MFMAH(a11h, bl1, c1);
            const int gc = kc0 + (tl << 4) + m16;
            #pragma unroll
            for (int r = 0; r < 4; r++) {
                if (c0[r] > bv0[r]) { bv0[r] = c0[r]; bc0[r] = gc; }
                if (c1[r] > bv1[r]) { bv1[r] = c1[r]; bc1[r] = gc; }
            }
            // col argmax: in-lane over 8 rows (rowset0 first -> smallest row)
            float v = c0[0]; int ri = (quad << 2);
            if (c0[1] > v) { v = c0[1]; ri = (quad << 2) + 1; }
            if (c0[2] > v) { v = c0[2]; ri = (quad << 2) + 2; }
            if (c0[3] > v) { v = c0[3]; ri = (quad << 2) + 3; }
            if (c1[0] > v) { v = c1[0]; ri = 16 + (quad << 2); }
            if (c1[1] > v) { v = c1[1]; ri = 16 + (quad << 2) + 1; }
            if (c1[2] > v) { v = c1[2]; ri = 16 + (quad << 2) + 2; }
            if (c1[3] > v) { v = c1[3]; ri = 16 + (quad << 2) + 3; }
            unsigned long long pk = packVR(v, wrow + ri);
            pk = max64(pk, shflx64(pk, 16));
            pk = max64(pk, shflx64(pk, 32));
            if (quad == 0) atomicMax(&colbest[(ch << 6) + (tl << 4) + m16], pk);
        }
    }
    #pragma unroll
    for (int r = 0; r < 4; r++) {
        unsigned long long p0 = packVR(bv0[r], bc0[r]);
        p0 = max64(p0, shflx64(p0, 1)); p0 = max64(p0, shflx64(p0, 2));
        p0 = max64(p0, shflx64(p0, 4)); p0 = max64(p0, shflx64(p0, 8));
        if (m16 == 0)
            atomicMax(rowP + ((size_t)bh << 11) + wrow + (quad << 2) + r, p0);
        unsigned long long p1 = packVR(bv1[r], bc1[r]);
        p1 = max64(p1, shflx64(p1, 1)); p1 = max64(p1, shflx64(p1, 2));
        p1 = max64(p1, shflx64(p1, 4)); p1 = max64(p1, shflx64(p1, 8));
        if (m16 == 0)
            atomicMax(rowP + ((size_t)bh << 11) + wrow + 16 + (quad << 2) + r, p1);
    }
    __syncthreads();
    for (int c = t; c < 1024; c += 256)
        atomicMax(colP + ((size_t)bh << 11) + (ks << 10) + c, colbest[c]);
}

// ---------------------------------------------------------------------------
// K3: cycle-consistency resolve -> vn[b,h,j] = valid*NEG*LOG2E - MFIX
// ---------------------------------------------------------------------------
__global__ __launch_bounds__(256) void resolve(const unsigned long long* __restrict__ q2kP,
        const unsigned long long* __restrict__ k2qP, const int* __restrict__ supp_mask,
        const float* __restrict__ supp_valid, float* __restrict__ vn)
{
    const int t = blockIdx.x * 256 + threadIdx.x;      // 32768 = B*H*NS
    const int bh = t >> 11, j = t & 2047, b = bh >> 3;
    const unsigned k2q = 0xFFFFFFFFu - (unsigned)(k2qP[t] & 0xFFFFFFFFull);
    const unsigned rm  = 0xFFFFFFFFu - (unsigned)(q2kP[(bh << 11) + k2q] & 0xFFFFFFFFull);
    const int asso = supp_mask[(b << 11) + j] == supp_mask[(b << 11) + (int)rm];
    const float valid = asso ? supp_valid[(b << 11) + j] : 1.0f;
    vn[t] = fmaf(valid, NEG_ * LOG2E_, -MFIX_);
}

// ---------------------------------------------------------------------------
// K4: fused attention, 32 rows/wave (2 rowsets share K/V frags), key-split
// x2 across blocks; p = exp2(s + vn) (fixed max), partial l and partial x
// (f32) written per ks; final GEMM folds the combine. dbuf staging,
// XCD-pinned.
// ---------------------------------------------------------------------------
__global__ __launch_bounds__(256) void attn_pv(
        const _Float16* __restrict__ qh, const _Float16* __restrict__ kh,
        const _Float16* __restrict__ vT, const float* __restrict__ vnG,
        float* __restrict__ xp, float* __restrict__ lp)
{
    __shared__ __attribute__((aligned(16))) _Float16 Ksh[2][2048];    // 8 KB
    __shared__ __attribute__((aligned(16))) _Float16 Vsh[2][2048];    // 8 KB
    __shared__ float vnL[1024];                                       // 4 KB
    __shared__ __attribute__((aligned(16))) _Float16 pbuf[4][2][640]; // 10 KB
    const int bx = blockIdx.x;
    const int bh = ((bx & 7) << 1) | (bx >> 8);
    const int rt = (bx >> 3) & 15;
    const int ks = (bx >> 7) & 1;
    const int t = threadIdx.x, w = t >> 6, lane = t & 63;
    const int m16 = lane & 15, quad = lane >> 4;
    const int rowbase = (rt << 7) + (w << 5);
    const size_t qoff0 = ((((size_t)bh << 11) + rowbase + m16) << 6) + (quad << 3);
    const size_t qoff1 = qoff0 + 1024;
    const f16x8_t a0 = load_h8(qh + qoff0), a1 = load_h8(qh + qoff0 + 32);
    const f16x8_t a2 = load_h8(qh + qoff1), a3 = load_h8(qh + qoff1 + 32);
    for (int c = t; c < 1024; c += 256) vnL[c] = vnG[(bh << 11) + (ks << 10) + c];
    const float KS = SCALE_ * LOG2E_;
    const int krow = lane >> 3, kblk = (lane & 7) ^ ((lane >> 3) & 7);
    const int vrow = lane >> 2, vblk = (lane & 3) ^ ((lane >> 3) & 3);
    const int e = m16 & 7;
    const int s00 = (quad ^ e) << 3, s01 = ((4 + quad) ^ e) << 3;
    const int vsw = (m16 >> 1) & 3;
    const f32x4_t z = {0.f, 0.f, 0.f, 0.f};
    f32x4_t xa0[4], xa1[4];
    #pragma unroll
    for (int nt = 0; nt < 4; nt++) { xa0[nt] = z; xa1[nt] = z; }
    float lr0[4] = {0.f, 0.f, 0.f, 0.f}, lr1[4] = {0.f, 0.f, 0.f, 0.f};
    const size_t kbel = ((size_t)bh << 11) * HD_;
    _Float16* pw0 = pbuf[w][0];
    _Float16* pw1 = pbuf[w][1];

    auto stage = [&](int buf, int ch) {
        const int kcg = (ks << 10) + (ch << 5);
        const size_t ce = kbel + (size_t)kcg * HD_;
        const size_t ve = ((size_t)(bh << 6) + (kcg >> 5)) << 11;
        #pragma unroll
        for (int ci = 0; ci < 2; ci++) {
            const int call = (w << 1) + ci;
            if (call < 4) {
                const _Float16* src = kh + ce + ((call * 8 + krow) << 6) + (kblk << 3);
                gload_lds16(src, &Ksh[buf][call << 9]);
            } else {
                const int j = call - 4;
                const _Float16* src = vT + ve + ((j * 16 + vrow) << 5) + (vblk << 3);
                gload_lds16(src, &Vsh[buf][j << 9]);
            }
        }
    };

    stage(0, 0);
    for (int ch = 0; ch < 32; ch++) {
        __syncthreads();
        if (ch + 1 < 32) stage((ch + 1) & 1, ch + 1);
        const _Float16* K = Ksh[ch & 1];
        const _Float16* V = Vsh[ch & 1];
        const f16x8_t b00 = load_h8(&K[(m16 << 6) + s00]);
        const f16x8_t b01 = load_h8(&K[(m16 << 6) + s01]);
        const f16x8_t b10 = load_h8(&K[((16 + m16) << 6) + s00]);
        const f16x8_t b11 = load_h8(&K[((16 + m16) << 6) + s01]);
        f32x4_t c00 = MFMAH(a0, b00, z); c00 = MFMAH(a1, b01, c00);
        f32x4_t c01 = MFMAH(a0, b10, z); c01 = MFMAH(a1, b11, c01);
        f32x4_t c10 = MFMAH(a2, b00, z); c10 = MFMAH(a3, b01, c10);
        f32x4_t c11 = MFMAH(a2, b10, z); c11 = MFMAH(a3, b11, c11);
        const float vn0 = vnL[(ch << 5) + m16], vn1 = vnL[(ch << 5) + 16 + m16];
        #pragma unroll
        for (int r = 0; r < 4; r++) {
            const float p00 = exp2f(fmaf(c00[r], KS, vn0));
            const float p01 = exp2f(fmaf(c01[r], KS, vn1));
            lr0[r] += p00 + p01;
            pw0[(((quad << 2) + r) * 40) + m16]      = (_Float16)p00;
            pw0[(((quad << 2) + r) * 40) + 16 + m16] = (_Float16)p01;
            const float p10 = exp2f(fmaf(c10[r], KS, vn0));
            const float p11 = exp2f(fmaf(c11[r], KS, vn1));
            lr1[r] += p10 + p11;
            pw1[(((quad << 2) + r) * 40) + m16]      = (_Float16)p10;
            pw1[(((quad << 2) + r) * 40) + 16 + m16] = (_Float16)p11;
        }
        __threadfence_block();   // order P writes before same-wave P reads
        const f16x8_t pa0 = load_h8(&pw0[m16 * 40 + (quad << 3)]);
        const f16x8_t pa1 = load_h8(&pw1[m16 * 40 + (quad << 3)]);
        #pragma unroll
        for (int nt = 0; nt < 4; nt++) {
            const f16x8_t vb = load_h8(&V[((nt * 16 + m16) << 5) + ((quad ^ vsw) << 3)]);
            xa0[nt] = MFMAH(pa0, vb, xa0[nt]);
            xa1[nt] = MFMAH(pa1, vb, xa1[nt]);
        }
    }
    #pragma unroll
    for (int d = 1; d < 16; d <<= 1) {
        #pragma unroll
        for (int r = 0; r < 4; r++) {
            lr0[r] += __shfl_xor(lr0[r], d, 64);
            lr1[r] += __shfl_xor(lr1[r], d, 64);
        }
    }
    const int b = bh >> 3, h = bh & 7;
    if (m16 == 0) {
        #pragma unroll
        for (int r = 0; r < 4; r++) {
            lp[((size_t)ks << 15) + (bh << 11) + rowbase + (quad << 2) + r] = lr0[r];
            lp[((size_t)ks << 15) + (bh << 11) + rowbase + 16 + (quad << 2) + r] = lr1[r];
        }
    }
    const size_t xbase = ((size_t)ks << 21);
    #pragma unroll
    for (int r = 0; r < 4; r++) {
        const int row0 = rowbase + (quad << 2) + r;
        const int row1 = row0 + 16;
        #pragma unroll
        for (int nt = 0; nt < 4; nt++) {
            xp[xbase + (((size_t)(b << 11) + row0) << 9) + (h << 6) + (nt << 4) + m16] = xa0[nt][r];
            xp[xbase + (((size_t)(b << 11) + row1) << 9) + (h << 6) + (nt << 4) + m16] = xa1[nt][r];
        }
    }
}

// ---------------------------------------------------------------------------
// K5: output GEMM. A = (xp0 + xp1) * (1/(l0+l1)), split to f16 hi/lo on the
// fly (per K-chunk = per head, so linv is one scalar per rowset per chunk).
// out[m,j] = sum_k A[m,k]*Wproj[j,k], fp32 out.
// ---------------------------------------------------------------------------
__global__ __launch_bounds__(256) void out_gemm(
        const float* __restrict__ xp, const float* __restrict__ lp,
        const _Float16* __restrict__ Wh, const _Float16* __restrict__ Wl,
        float* __restrict__ outF)
{
    __shared__ __attribute__((aligned(16))) _Float16 Wsh[2][2][4096];  // 32 KB
    const int t = threadIdx.x, w = t >> 6, lane = t & 63;
    const int m16 = lane & 15, quad = lane >> 4;
    const int bm = blockIdx.x << 7, bn = blockIdx.y << 6;
    const int r0 = bm + (w << 5) + m16, r1 = r0 + 16;
    const int krow = lane >> 3, kblk = (lane & 7) ^ (krow & 7);
    const int e = m16 & 7;
    const int s00 = (quad ^ e) << 3, s01 = ((4 + quad) ^ e) << 3;
    const f32x4_t z = {0.f, 0.f, 0.f, 0.f};
    f32x4_t acc[2][4];
    #pragma unroll
    for (int rs = 0; rs < 2; rs++)
        #pragma unroll
        for (int tl = 0; tl < 4; tl++) acc[rs][tl] = z;

    auto stageW = [&](int buf, int kc) {
        #pragma unroll
        for (int ci = 0; ci < 4; ci++) {
            const int pp = (w << 2) + ci;
            const int s = pp >> 3, pj = pp & 7;
            const _Float16* src = (s ? Wl : Wh)
                + (size_t)(bn + (pj << 3) + krow) * C_ + kc + (kblk << 3);
            gload_lds16(src, &Wsh[buf][s][pj << 9]);
        }
    };
    auto loadA = [&](int ch, f16x8_t* d) {
        const int kc = ch << 6;                       // head = ch
        #pragma unroll
        for (int rs = 0; rs < 2; rs++) {
            const int r = rs ? r1 : r0;
            const int b = r >> 11, n = r & 2047;
            const size_t li = ((size_t)((b << 3) + ch) << 11) + n;
            const float linv = 1.0f / (lp[li] + lp[32768 + li]);
            const size_t base = ((size_t)r << 9) + kc + (quad << 3);
            #pragma unroll
            for (int seg = 0; seg < 2; seg++) {
                f16x8_t hv, lv;
                #pragma unroll
                for (int i = 0; i < 8; i++) {
                    const size_t o = base + seg * 32 + i;
                    const float x = (xp[o] + xp[2097152 + o]) * linv;
                    const _Float16 hh = (_Float16)x;
                    hv[i] = hh;
                    lv[i] = (_Float16)(x - (float)hh);
                }
                d[rs * 4 + seg] = hv;
                d[rs * 4 + seg + 2] = lv;
            }
        }
    };

    f16x8_t cA[8], nA[8];
    stageW(0, 0);
    loadA(0, cA);
    for (int ch = 0; ch < 8; ch++) {
        __syncthreads();
        if (ch + 1 < 8) {
            stageW((ch + 1) & 1, (ch + 1) << 6);
            loadA(ch + 1, nA);
        }
        const _Float16* W0 = Wsh[ch & 1][0];
        const _Float16* W1 = Wsh[ch & 1][1];
        #pragma unroll
        for (int tl = 0; tl < 4; tl++) {
            const int j64 = ((tl << 4) + m16) << 6;
            const f16x8_t bh0 = load_h8(&W0[j64 + s00]);
            const f16x8_t bh1 = load_h8(&W0[j64 + s01]);
            const f16x8_t bl0 = load_h8(&W1[j64 + s00]);
            const f16x8_t bl1 = load_h8(&W1[j64 + s01]);
            f32x4_t c0 = acc[0][tl];
            c0 = MFMAH(cA[0], bh0, c0); c0 = MFMAH(cA[1], bh1, c0);
            c0 = MFMAH(cA[2], bh0, c0); c0 = MFMAH(cA[3], bh1, c0);
            c0 = MFMAH(cA[0], bl0, c0); c0 = MFMAH(cA[1], bl1, c0);
            acc[0][tl] = c0;
            f32x4_t c1 = acc[1][tl];
            c1 = MFMAH(cA[4], bh0, c1); c1 = MFMAH(cA[5], bh1, c1);
            c1 = MFMAH(cA[6], bh0, c1); c1 = MFMAH(cA[7], bh1, c1);
            c1 = MFMAH(cA[4], bl0, c1); c1 = MFMAH(cA[5], bl1, c1);
            acc[1][tl] = c1;
        }
        #pragma unroll
        for (int i = 0; i < 8; i++) cA[i] = nA[i];
    }
    #pragma unroll
    for (int rs = 0; rs < 2; rs++) {
        #pragma unroll
        for (int tl = 0; tl < 4; tl++) {
            #pragma unroll
            for (int r = 0; r < 4; r++) {
                const int gr = bm + (w << 5) + (rs << 4) + (quad << 2) + r;
                const int gj = bn + (tl << 4) + m16;
                outF[(size_t)gr * C_ + gj] = acc[rs][tl][r];
            }
        }
    }
}

// ---------------------------------------------------------------------------
extern "C" void kernel_launch(void* const* d_in, const int* in_sizes, int n_in,
                              void* d_out, int out_size, void* d_ws, size_t ws_size,
                              hipStream_t stream) {
    const float* q  = (const float*)d_in[0];
    const float* k  = (const float*)d_in[1];
    const float* v  = (const float*)d_in[2];
    const float* supp_valid = (const float*)d_in[3];
    const int*   supp_mask  = (const int*)d_in[4];
    const float* Wq = (const float*)d_in[5];
    const float* Wk = (const float*)d_in[6];
    const float* Wv = (const float*)d_in[7];
    const float* Wp = (const float*)d_in[8];
    float* out = (float*)d_out;

    char* p = (char*)d_ws;
    _Float16* qhi = (_Float16*)p;      p += 4194304;   // [bh][n][d] f16 splits
    _Float16* qlo = (_Float16*)p;      p += 4194304;
    _Float16* khi = (_Float16*)p;      p += 4194304;
    _Float16* klo = (_Float16*)p;      p += 4194304;
    _Float16* vT  = (_Float16*)p;      p += 4194304;   // [bh] chunk-tiled
    float* xp     = (float*)p;         p += 16777216;  // [2][4096][512] f32
    _Float16* wH  = (_Float16*)p;      p += 2097152;   // [4][512*512]
    _Float16* wL  = (_Float16*)p;      p += 2097152;
    unsigned long long* q2kP = (unsigned long long*)p; p += 262144;
    unsigned long long* k2qP = (unsigned long long*)p; p += 262144;
    float* lp = (float*)p;             p += 262144;    // [2][16][2048]
    float* validNeg = (float*)p;       p += 131072;

    hipMemsetAsync(q2kP, 0, 524288, stream);           // rowP + colP zero init

    dim3 bG(256);
    wsplit4<<<dim3(256, 4), bG, 0, stream>>>(Wq, Wk, Wv, Wp, wH, wL);
    proj_gemm<<<dim3(32, 8, 3), bG, 0, stream>>>(q, k, v, wH, wL,
                                                 qhi, qlo, khi, klo, vT);

    argmax_mfma<<<512, bG, 0, stream>>>(qhi, qlo, khi, klo, q2kP, k2qP);

    resolve<<<128, bG, 0, stream>>>(q2kP, k2qP, supp_mask, supp_valid, validNeg);

    attn_pv<<<512, bG, 0, stream>>>(qhi, khi, vT, validNeg, xp, lp);

    out_gemm<<<dim3(32, 8), bG, 0, stream>>>(xp, lp,
                                             wH + 3 * 262144, wL + 3 * 262144, out);
}

// Round 7
// 221.935 us; speedup vs baseline: 2.8402x; 1.0547x over previous
//
#include <hip/hip_runtime.h>
#include <hip/hip_bf16.h>
#include <stdint.h>

#define H_ 8
#define NS_ 2048
#define C_ 512
#define HD_ 64
#define SCALE_ 0.125f
#define NEG_ -10000.0f
#define LOG2E_ 1.4426950408889634f
#define MFIX_ 4.0f

typedef _Float16 f16x8_t __attribute__((ext_vector_type(8)));
typedef _Float16 f16x4_t __attribute__((ext_vector_type(4)));
typedef float f32x4_t __attribute__((ext_vector_type(4)));

#define MFMAH(a, b, c) __builtin_amdgcn_mfma_f32_16x16x32_f16(a, b, c, 0, 0, 0)

__device__ inline f16x8_t load_h8(const _Float16* p) {
    return *reinterpret_cast<const f16x8_t*>(p);
}

// async global->LDS, 16B per lane; LDS dest = uniform base + lane*16
__device__ inline void gload_lds16(const void* g, void* l) {
    __builtin_amdgcn_global_load_lds(
        (const __attribute__((address_space(1))) unsigned int*)g,
        (__attribute__((address_space(3))) unsigned int*)l, 16, 0, 0);
}

__device__ inline unsigned orderF(float v) {
    unsigned u = __float_as_uint(v);
    return (u & 0x80000000u) ? ~u : (u | 0x80000000u);
}
__device__ inline unsigned long long packVR(float v, int idx) {
    return ((unsigned long long)orderF(v) << 32) | (unsigned)(~idx);
}
__device__ inline unsigned long long max64(unsigned long long a, unsigned long long b) {
    return a > b ? a : b;
}
__device__ inline unsigned long long shflx64(unsigned long long x, int m) {
    unsigned lo = (unsigned)x, hi = (unsigned)(x >> 32);
    lo = __shfl_xor(lo, m, 64);
    hi = __shfl_xor(hi, m, 64);
    return ((unsigned long long)hi << 32) | lo;
}

// ---------------------------------------------------------------------------
// K0: all four 512x512 weights -> f16 hi/lo splits in one launch.
// ---------------------------------------------------------------------------
__global__ __launch_bounds__(256) void wsplit4(
        const float* __restrict__ w0, const float* __restrict__ w1,
        const float* __restrict__ w2, const float* __restrict__ w3,
        _Float16* __restrict__ hi, _Float16* __restrict__ lo)
{
    const int i = blockIdx.x * 256 + threadIdx.x;            // 65536 float4 / W
    const int y = blockIdx.y;
    const float* src = (y == 0) ? w0 : (y == 1) ? w1 : (y == 2) ? w2 : w3;
    const float4 v = reinterpret_cast<const float4*>(src)[i];
    f16x4_t hv, lv;
    hv[0] = (_Float16)v.x; hv[1] = (_Float16)v.y;
    hv[2] = (_Float16)v.z; hv[3] = (_Float16)v.w;
    lv[0] = (_Float16)(v.x - (float)hv[0]);
    lv[1] = (_Float16)(v.y - (float)hv[1]);
    lv[2] = (_Float16)(v.z - (float)hv[2]);
    lv[3] = (_Float16)(v.w - (float)hv[3]);
    const size_t o = ((size_t)y << 16) + i;                  // float4 index
    reinterpret_cast<f16x4_t*>(hi)[o] = hv;
    reinterpret_cast<f16x4_t*>(lo)[o] = lv;
}

// ---------------------------------------------------------------------------
// K1: projection GEMM (q/k/v via grid.z). 3-term split-f16 MFMA (~fp32).
// z<2: hi/lo split out [bh][n][d]; z==2: V tiled [bh][key>>5][d][k'] with
// k' = ((key&15)<<1)|((key>>4)&1)  (interleaved to match attn_pv's packed P).
// ---------------------------------------------------------------------------
__global__ __launch_bounds__(256) void proj_gemm(
        const float* __restrict__ qin, const float* __restrict__ kin,
        const float* __restrict__ vin,
        const _Float16* __restrict__ wHall, const _Float16* __restrict__ wLall,
        _Float16* __restrict__ qhi, _Float16* __restrict__ qlo,
        _Float16* __restrict__ khi, _Float16* __restrict__ klo,
        _Float16* __restrict__ vT)
{
    __shared__ __attribute__((aligned(16))) _Float16 Wsh[2][2][4096];  // 32 KB
    const int zz = blockIdx.z;
    const float* A32 = (zz == 0) ? qin : (zz == 1) ? kin : vin;
    const _Float16* Wh = wHall + ((size_t)zz << 18);
    const _Float16* Wl = wLall + ((size_t)zz << 18);
    const int t = threadIdx.x, w = t >> 6, lane = t & 63;
    const int m16 = lane & 15, quad = lane >> 4;
    const int bm = blockIdx.x << 7, bn = blockIdx.y << 6;
    const int r0 = bm + (w << 5) + m16, r1 = r0 + 16;
    const int krow = lane >> 3, kblk = (lane & 7) ^ (krow & 7);
    const int e = m16 & 7;
    const int s00 = (quad ^ e) << 3, s01 = ((4 + quad) ^ e) << 3;
    const f32x4_t z = {0.f, 0.f, 0.f, 0.f};
    f32x4_t acc[2][4];
    #pragma unroll
    for (int rs = 0; rs < 2; rs++)
        #pragma unroll
        for (int tl = 0; tl < 4; tl++) acc[rs][tl] = z;

    auto stageW = [&](int buf, int kc) {
        #pragma unroll
        for (int ci = 0; ci < 4; ci++) {
            const int pp = (w << 2) + ci;
            const int s = pp >> 3, pj = pp & 7;
            const _Float16* src = (s ? Wl : Wh)
                + (size_t)(bn + (pj << 3) + krow) * C_ + kc + (kblk << 3);
            gload_lds16(src, &Wsh[buf][s][pj << 9]);
        }
    };
    auto loadA = [&](int kc, f16x8_t* d) {
        #pragma unroll
        for (int rs = 0; rs < 2; rs++) {
            const float* pr = A32 + (size_t)(rs ? r1 : r0) * C_ + kc + (quad << 3);
            #pragma unroll
            for (int seg = 0; seg < 2; seg++) {
                f16x8_t hv, lv;
                #pragma unroll
                for (int i = 0; i < 8; i++) {
                    const float x = pr[seg * 32 + i];
                    const _Float16 hh = (_Float16)x;
                    hv[i] = hh;
                    lv[i] = (_Float16)(x - (float)hh);
                }
                d[rs * 4 + seg] = hv;
                d[rs * 4 + seg + 2] = lv;
            }
        }
    };

    f16x8_t cA[8], nA[8];
    stageW(0, 0);
    loadA(0, cA);
    for (int ch = 0; ch < 8; ch++) {
        __syncthreads();
        if (ch + 1 < 8) {
            stageW((ch + 1) & 1, (ch + 1) << 6);
            loadA((ch + 1) << 6, nA);
        }
        const _Float16* W0 = Wsh[ch & 1][0];
        const _Float16* W1 = Wsh[ch & 1][1];
        #pragma unroll
        for (int tl = 0; tl < 4; tl++) {
            const int j64 = ((tl << 4) + m16) << 6;
            const f16x8_t bh0 = load_h8(&W0[j64 + s00]);
            const f16x8_t bh1 = load_h8(&W0[j64 + s01]);
            const f16x8_t bl0 = load_h8(&W1[j64 + s00]);
            const f16x8_t bl1 = load_h8(&W1[j64 + s01]);
            f32x4_t c0 = acc[0][tl];
            c0 = MFMAH(cA[0], bh0, c0); c0 = MFMAH(cA[1], bh1, c0);
            c0 = MFMAH(cA[2], bh0, c0); c0 = MFMAH(cA[3], bh1, c0);
            c0 = MFMAH(cA[0], bl0, c0); c0 = MFMAH(cA[1], bl1, c0);
            acc[0][tl] = c0;
            f32x4_t c1 = acc[1][tl];
            c1 = MFMAH(cA[4], bh0, c1); c1 = MFMAH(cA[5], bh1, c1);
            c1 = MFMAH(cA[6], bh0, c1); c1 = MFMAH(cA[7], bh1, c1);
            c1 = MFMAH(cA[4], bl0, c1); c1 = MFMAH(cA[5], bl1, c1);
            acc[1][tl] = c1;
        }
        #pragma unroll
        for (int i = 0; i < 8; i++) cA[i] = nA[i];
    }
    const int by = blockIdx.y;
    _Float16* o1 = (zz == 0) ? qhi : khi;
    _Float16* o2 = (zz == 0) ? qlo : klo;
    #pragma unroll
    for (int rs = 0; rs < 2; rs++) {
        #pragma unroll
        for (int tl = 0; tl < 4; tl++) {
            #pragma unroll
            for (int r = 0; r < 4; r++) {
                const int gr = bm + (w << 5) + (rs << 4) + (quad << 2) + r;
                const float val = acc[rs][tl][r];
                const int b = gr >> 11, n = gr & 2047;
                const int d = (tl << 4) + m16;
                const int bh = (b << 3) + by;
                if (zz == 2) {
                    const int kp = ((n & 15) << 1) | ((n >> 4) & 1);
                    vT[(((size_t)((bh << 6) + (n >> 5)) << 6) + d) * 32 + kp] = (_Float16)val;
                } else {
                    const size_t idx = ((((size_t)bh << 11) + n) << 6) + d;
                    const _Float16 hh = (_Float16)val;
                    o1[idx] = hh;
                    o2[idx] = (_Float16)(val - (float)hh);
                }
            }
        }
    }
}

// ---------------------------------------------------------------------------
// K2: MFMA split-f16 argmax. 32 rows/wave, 64-key chunks, dbuf LDS staging,
// key-space split x4 (4 blocks/CU). Row argmax -> global atomicMax; col
// argmax -> in-lane reduce, quad butterfly, LDS atomicMax, block merge.
// XCD-pinned: bh pair {2x,2x+1} on XCD x.
// ---------------------------------------------------------------------------
__global__ __launch_bounds__(256) void argmax_mfma(
        const _Float16* __restrict__ qhi, const _Float16* __restrict__ qlo,
        const _Float16* __restrict__ khi, const _Float16* __restrict__ klo,
        unsigned long long* __restrict__ rowP, unsigned long long* __restrict__ colP)
{
    __shared__ __attribute__((aligned(16))) _Float16 Ksh[2][2][4096];  // 32 KB
    __shared__ unsigned long long colbest[512];                        // 4 KB
    const int bx = blockIdx.x;
    const int bh = ((bx & 7) << 1) | (bx >> 9);
    const int mid = (bx >> 3) & 63;
    const int rt = mid & 15;
    const int ks = mid >> 4;                               // 0..3
    const int t = threadIdx.x, w = t >> 6, lane = t & 63;
    const int m16 = lane & 15, quad = lane >> 4;
    const int wrow = (rt << 7) + (w << 5);
    const size_t qoff0 = ((((size_t)bh << 11) + wrow + m16) << 6) + (quad << 3);
    const size_t qoff1 = qoff0 + 1024;
    const f16x8_t a00h = load_h8(qhi + qoff0), a01h = load_h8(qhi + qoff0 + 32);
    const f16x8_t a00l = load_h8(qlo + qoff0), a01l = load_h8(qlo + qoff0 + 32);
    const f16x8_t a10h = load_h8(qhi + qoff1), a11h = load_h8(qhi + qoff1 + 32);
    const f16x8_t a10l = load_h8(qlo + qoff1), a11l = load_h8(qlo + qoff1 + 32);
    for (int c = t; c < 512; c += 256) colbest[c] = 0;
    const int krow = lane >> 3, kblk = (lane & 7) ^ (krow & 7);
    const int e = m16 & 7;
    const int s00 = (quad ^ e) << 3, s01 = ((4 + quad) ^ e) << 3;
    const size_t kbase = (((size_t)bh << 11) + (ks << 9)) << 6;
    float bv0[4] = {-3.4e38f, -3.4e38f, -3.4e38f, -3.4e38f};
    float bv1[4] = {-3.4e38f, -3.4e38f, -3.4e38f, -3.4e38f};
    int bc0[4] = {0, 0, 0, 0}, bc1[4] = {0, 0, 0, 0};
    const f32x4_t z = {0.f, 0.f, 0.f, 0.f};

    auto stage = [&](int buf, int cidx) {
        const size_t ce = kbase + ((size_t)cidx << 12);
        #pragma unroll
        for (int ci = 0; ci < 4; ci++) {
            const int pp = (w << 2) + ci;
            const int s = pp >> 3, pj = pp & 7;
            const _Float16* src = (s ? klo : khi) + ce + (((pj << 3) + krow) << 6) + (kblk << 3);
            gload_lds16(src, &Ksh[buf][s][pj << 9]);
        }
    };

    stage(0, 0);
    for (int ch = 0; ch < 8; ch++) {
        __syncthreads();
        if (ch + 1 < 8) stage((ch + 1) & 1, ch + 1);
        const _Float16* K0 = Ksh[ch & 1][0];
        const _Float16* K1 = Ksh[ch & 1][1];
        const int kc0 = (ks << 9) + (ch << 6);
        #pragma unroll
        for (int tl = 0; tl < 4; tl++) {
            const int j64 = ((tl << 4) + m16) << 6;
            const f16x8_t bh0 = load_h8(&K0[j64 + s00]);
            const f16x8_t bh1 = load_h8(&K0[j64 + s01]);
            const f16x8_t bl0 = load_h8(&K1[j64 + s00]);
            const f16x8_t bl1 = load_h8(&K1[j64 + s01]);
            f32x4_t c0 = MFMAH(a00h, bh0, z);
            c0 = MFMAH(a01h, bh1, c0);
            c0 = MFMAH(a00l, bh0, c0); c0 = MFMAH(a01l, bh1, c0);
            c0 = MFMAH(a00h, bl0, c0); c0 = MFMAH(a01h, bl1, c0);
            f32x4_t c1 = MFMAH(a10h, bh0, z);
            c1 = MFMAH(a11h, bh1, c1);
            c1 = MFMAH(a10l, bh0, c1); c1 = MFMAH(a11l, bh1, c1);
            c1 = MFMAH(a10h, bl0, c1); c1 = MFMAH(a11h, bl1, c1);
            const int gc = kc0 + (tl << 4) + m16;
            #pragma unroll
            for (int r = 0; r < 4; r++) {
                if (c0[r] > bv0[r]) { bv0[r] = c0[r]; bc0[r] = gc; }
                if (c1[r] > bv1[r]) { bv1[r] = c1[r]; bc1[r] = gc; }
            }
            // col argmax: in-lane over 8 rows (rowset0 first -> smallest row)
            float v = c0[0]; int ri = (quad << 2);
            if (c0[1] > v) { v = c0[1]; ri = (quad << 2) + 1; }
            if (c0[2] > v) { v = c0[2]; ri = (quad << 2) + 2; }
            if (c0[3] > v) { v = c0[3]; ri = (quad << 2) + 3; }
            if (c1[0] > v) { v = c1[0]; ri = 16 + (quad << 2); }
            if (c1[1] > v) { v = c1[1]; ri = 16 + (quad << 2) + 1; }
            if (c1[2] > v) { v = c1[2]; ri = 16 + (quad << 2) + 2; }
            if (c1[3] > v) { v = c1[3]; ri = 16 + (quad << 2) + 3; }
            unsigned long long pk = packVR(v, wrow + ri);
            pk = max64(pk, shflx64(pk, 16));
            pk = max64(pk, shflx64(pk, 32));
            if (quad == 0) atomicMax(&colbest[(ch << 6) + (tl << 4) + m16], pk);
        }
    }
    #pragma unroll
    for (int r = 0; r < 4; r++) {
        unsigned long long p0 = packVR(bv0[r], bc0[r]);
        p0 = max64(p0, shflx64(p0, 1)); p0 = max64(p0, shflx64(p0, 2));
        p0 = max64(p0, shflx64(p0, 4)); p0 = max64(p0, shflx64(p0, 8));
        if (m16 == 0)
            atomicMax(rowP + ((size_t)bh << 11) + wrow + (quad << 2) + r, p0);
        unsigned long long p1 = packVR(bv1[r], bc1[r]);
        p1 = max64(p1, shflx64(p1, 1)); p1 = max64(p1, shflx64(p1, 2));
        p1 = max64(p1, shflx64(p1, 4)); p1 = max64(p1, shflx64(p1, 8));
        if (m16 == 0)
            atomicMax(rowP + ((size_t)bh << 11) + wrow + 16 + (quad << 2) + r, p1);
    }
    __syncthreads();
    for (int c = t; c < 512; c += 256)
        atomicMax(colP + ((size_t)bh << 11) + (ks << 9) + c, colbest[c]);
}

// ---------------------------------------------------------------------------
// K3: cycle-consistency resolve -> vn[b,h,j] = valid*NEG*LOG2E - MFIX
// ---------------------------------------------------------------------------
__global__ __launch_bounds__(256) void resolve(const unsigned long long* __restrict__ q2kP,
        const unsigned long long* __restrict__ k2qP, const int* __restrict__ supp_mask,
        const float* __restrict__ supp_valid, float* __restrict__ vn)
{
    const int t = blockIdx.x * 256 + threadIdx.x;      // 32768 = B*H*NS
    const int bh = t >> 11, j = t & 2047, b = bh >> 3;
    const unsigned k2q = 0xFFFFFFFFu - (unsigned)(k2qP[t] & 0xFFFFFFFFull);
    const unsigned rm  = 0xFFFFFFFFu - (unsigned)(q2kP[(bh << 11) + k2q] & 0xFFFFFFFFull);
    const int asso = supp_mask[(b << 11) + j] == supp_mask[(b << 11) + (int)rm];
    const float valid = asso ? supp_valid[(b << 11) + j] : 1.0f;
    vn[t] = fmaf(valid, NEG_ * LOG2E_, -MFIX_);
}

// ---------------------------------------------------------------------------
// K4: fused attention. 16 rows/wave, 1024 blocks (4/CU). p = exp2(s+vn)
// (fixed max); P packed as (p0,p1) u32 pairs into a stride-20-dword LDS
// strip (k' interleaved order, matching vT); l accumulated via ones-MFMA on
// the matrix pipe; partial x (f32) + l per ks; out_gemm folds the combine.
// ---------------------------------------------------------------------------
__global__ __launch_bounds__(256) void attn_pv(
        const _Float16* __restrict__ qh, const _Float16* __restrict__ kh,
        const _Float16* __restrict__ vT, const float* __restrict__ vnG,
        float* __restrict__ xp, float* __restrict__ lp)
{
    __shared__ __attribute__((aligned(16))) _Float16 Ksh[2][2048];    // 8 KB
    __shared__ __attribute__((aligned(16))) _Float16 Vsh[2][2048];    // 8 KB
    __shared__ float vnL[1024];                                       // 4 KB
    __shared__ __attribute__((aligned(16))) unsigned pbuf[4][320];    // 5 KB
    const int bx = blockIdx.x;
    const int bh = ((bx & 7) << 1) | (bx >> 9);
    const int mid = (bx >> 3) & 63;
    const int rt = mid & 31, ks = mid >> 5;
    const int t = threadIdx.x, w = t >> 6, lane = t & 63;
    const int m16 = lane & 15, quad = lane >> 4;
    const int rowbase = (rt << 6) + (w << 4);
    const size_t qoff = ((((size_t)bh << 11) + rowbase + m16) << 6) + (quad << 3);
    const f16x8_t a0 = load_h8(qh + qoff), a1 = load_h8(qh + qoff + 32);
    for (int c = t; c < 1024; c += 256) vnL[c] = vnG[(bh << 11) + (ks << 10) + c];
    const float KS = SCALE_ * LOG2E_;
    const int krow = lane >> 3, kblk = (lane & 7) ^ ((lane >> 3) & 7);
    const int vrow = lane >> 2, vblk = (lane & 3) ^ ((lane >> 3) & 3);
    const int e = m16 & 7;
    const int s00 = (quad ^ e) << 3, s01 = ((4 + quad) ^ e) << 3;
    const int vsw = (m16 >> 1) & 3;
    f16x8_t ones;
    #pragma unroll
    for (int i = 0; i < 8; i++) ones[i] = (_Float16)1.0f;
    const f32x4_t z = {0.f, 0.f, 0.f, 0.f};
    f32x4_t xacc[4];
    #pragma unroll
    for (int nt = 0; nt < 4; nt++) xacc[nt] = z;
    f32x4_t lacc = z;
    const size_t kbel = ((size_t)bh << 11) * HD_;
    unsigned* pw = pbuf[w];

    auto stage = [&](int buf, int ch) {
        const int kcg = (ks << 10) + (ch << 5);
        const size_t ce = kbel + (size_t)kcg * HD_;
        const size_t ve = ((size_t)(bh << 6) + (kcg >> 5)) << 11;
        #pragma unroll
        for (int ci = 0; ci < 2; ci++) {
            const int call = (w << 1) + ci;
            if (call < 4) {
                const _Float16* src = kh + ce + ((call * 8 + krow) << 6) + (kblk << 3);
                gload_lds16(src, &Ksh[buf][call << 9]);
            } else {
                const int j = call - 4;
                const _Float16* src = vT + ve + ((j * 16 + vrow) << 5) + (vblk << 3);
                gload_lds16(src, &Vsh[buf][j << 9]);
            }
        }
    };

    stage(0, 0);
    for (int ch = 0; ch < 32; ch++) {
        __syncthreads();
        if (ch + 1 < 32) stage((ch + 1) & 1, ch + 1);
        const _Float16* K = Ksh[ch & 1];
        const _Float16* V = Vsh[ch & 1];
        const f16x8_t b00 = load_h8(&K[(m16 << 6) + s00]);
        const f16x8_t b01 = load_h8(&K[(m16 << 6) + s01]);
        const f16x8_t b10 = load_h8(&K[((16 + m16) << 6) + s00]);
        const f16x8_t b11 = load_h8(&K[((16 + m16) << 6) + s01]);
        f32x4_t c0 = MFMAH(a0, b00, z); c0 = MFMAH(a1, b01, c0);
        f32x4_t c1 = MFMAH(a0, b10, z); c1 = MFMAH(a1, b11, c1);
        const float vn0 = vnL[(ch << 5) + m16], vn1 = vnL[(ch << 5) + 16 + m16];
        #pragma unroll
        for (int r = 0; r < 4; r++) {
            const float p0 = exp2f(fmaf(c0[r], KS, vn0));
            const float p1 = exp2f(fmaf(c1[r], KS, vn1));
            union { _Float16 h[2]; unsigned u; } pk_;
            pk_.h[0] = (_Float16)p0;          // key kc+m16      -> k' = 2*m16
            pk_.h[1] = (_Float16)p1;          // key kc+16+m16   -> k' = 2*m16+1
            pw[((quad << 2) + r) * 20 + m16] = pk_.u;
        }
        __threadfence_block();   // order P writes before same-wave P reads
        const f16x8_t pa = *reinterpret_cast<const f16x8_t*>(&pw[m16 * 20 + (quad << 2)]);
        lacc = MFMAH(pa, ones, lacc);
        #pragma unroll
        for (int nt = 0; nt < 4; nt++) {
            const f16x8_t vb = load_h8(&V[((nt * 16 + m16) << 5) + ((quad ^ vsw) << 3)]);
            xacc[nt] = MFMAH(pa, vb, xacc[nt]);
        }
    }
    const int b = bh >> 3, h = bh & 7;
    if (m16 == 0) {
        #pragma unroll
        for (int r = 0; r < 4; r++)
            lp[((size_t)ks << 15) + (bh << 11) + rowbase + (quad << 2) + r] = lacc[r];
    }
    const size_t xbase = ((size_t)ks << 21);
    #pragma unroll
    for (int r = 0; r < 4; r++) {
        const int row = rowbase + (quad << 2) + r;
        #pragma unroll
        for (int nt = 0; nt < 4; nt++)
            xp[xbase + (((size_t)(b << 11) + row) << 9) + (h << 6) + (nt << 4) + m16] = xacc[nt][r];
    }
}

// ---------------------------------------------------------------------------
// K5: output GEMM. A = (xp0 + xp1) * (1/(l0+l1)), split to f16 hi/lo on the
// fly; out[m,j] = sum_k A[m,k]*Wproj[j,k], fp32 out.
// ---------------------------------------------------------------------------
__global__ __launch_bounds__(256) void out_gemm(
        const float* __restrict__ xp, const float* __restrict__ lp,
        const _Float16* __restrict__ Wh, const _Float16* __restrict__ Wl,
        float* __restrict__ outF)
{
    __shared__ __attribute__((aligned(16))) _Float16 Wsh[2][2][4096];  // 32 KB
    const int t = threadIdx.x, w = t >> 6, lane = t & 63;
    const int m16 = lane & 15, quad = lane >> 4;
    const int bm = blockIdx.x << 7, bn = blockIdx.y << 6;
    const int r0 = bm + (w << 5) + m16, r1 = r0 + 16;
    const int krow = lane >> 3, kblk = (lane & 7) ^ (krow & 7);
    const int e = m16 & 7;
    const int s00 = (quad ^ e) << 3, s01 = ((4 + quad) ^ e) << 3;
    const f32x4_t z = {0.f, 0.f, 0.f, 0.f};
    f32x4_t acc[2][4];
    #pragma unroll
    for (int rs = 0; rs < 2; rs++)
        #pragma unroll
        for (int tl = 0; tl < 4; tl++) acc[rs][tl] = z;

    auto stageW = [&](int buf, int kc) {
        #pragma unroll
        for (int ci = 0; ci < 4; ci++) {
            const int pp = (w << 2) + ci;
            const int s = pp >> 3, pj = pp & 7;
            const _Float16* src = (s ? Wl : Wh)
                + (size_t)(bn + (pj << 3) + krow) * C_ + kc + (kblk << 3);
            gload_lds16(src, &Wsh[buf][s][pj << 9]);
        }
    };
    auto loadA = [&](int ch, f16x8_t* d) {
        const int kc = ch << 6;                       // head = ch
        #pragma unroll
        for (int rs = 0; rs < 2; rs++) {
            const int r = rs ? r1 : r0;
            const int b = r >> 11, n = r & 2047;
            const size_t li = ((size_t)((b << 3) + ch) << 11) + n;
            const float linv = 1.0f / (lp[li] + lp[32768 + li]);
            const size_t base = ((size_t)r << 9) + kc + (quad << 3);
            #pragma unroll
            for (int seg = 0; seg < 2; seg++) {
                f16x8_t hv, lv;
                #pragma unroll
                for (int i = 0; i < 8; i++) {
                    const size_t o = base + seg * 32 + i;
                    const float x = (xp[o] + xp[2097152 + o]) * linv;
                    const _Float16 hh = (_Float16)x;
                    hv[i] = hh;
                    lv[i] = (_Float16)(x - (float)hh);
                }
                d[rs * 4 + seg] = hv;
                d[rs * 4 + seg + 2] = lv;
            }
        }
    };

    f16x8_t cA[8], nA[8];
    stageW(0, 0);
    loadA(0, cA);
    for (int ch = 0; ch < 8; ch++) {
        __syncthreads();
        if (ch + 1 < 8) {
            stageW((ch + 1) & 1, (ch + 1) << 6);
            loadA(ch + 1, nA);
        }
        const _Float16* W0 = Wsh[ch & 1][0];
        const _Float16* W1 = Wsh[ch & 1][1];
        #pragma unroll
        for (int tl = 0; tl < 4; tl++) {
            const int j64 = ((tl << 4) + m16) << 6;
            const f16x8_t bh0 = load_h8(&W0[j64 + s00]);
            const f16x8_t bh1 = load_h8(&W0[j64 + s01]);
            const f16x8_t bl0 = load_h8(&W1[j64 + s00]);
            const f16x8_t bl1 = load_h8(&W1[j64 + s01]);
            f32x4_t c0 = acc[0][tl];
            c0 = MFMAH(cA[0], bh0, c0); c0 = MFMAH(cA[1], bh1, c0);
            c0 = MFMAH(cA[2], bh0, c0); c0 = MFMAH(cA[3], bh1, c0);
            c0 = MFMAH(cA[0], bl0, c0); c0 = MFMAH(cA[1], bl1, c0);
            acc[0][tl] = c0;
            f32x4_t c1 = acc[1][tl];
            c1 = MFMAH(cA[4], bh0, c1); c1 = MFMAH(cA[5], bh1, c1);
            c1 = MFMAH(cA[6], bh0, c1); c1 = MFMAH(cA[7], bh1, c1);
            c1 = MFMAH(cA[4], bl0, c1); c1 = MFMAH(cA[5], bl1, c1);
            acc[1][tl] = c1;
        }
        #pragma unroll
        for (int i = 0; i < 8; i++) cA[i] = nA[i];
    }
    #pragma unroll
    for (int rs = 0; rs < 2; rs++) {
        #pragma unroll
        for (int tl = 0; tl < 4; tl++) {
            #pragma unroll
            for (int r = 0; r < 4; r++) {
                const int gr = bm + (w << 5) + (rs << 4) + (quad << 2) + r;
                const int gj = bn + (tl << 4) + m16;
                outF[(size_t)gr * C_ + gj] = acc[rs][tl][r];
            }
        }
    }
}

// ---------------------------------------------------------------------------
extern "C" void kernel_launch(void* const* d_in, const int* in_sizes, int n_in,
                              void* d_out, int out_size, void* d_ws, size_t ws_size,
                              hipStream_t stream) {
    const float* q  = (const float*)d_in[0];
    const float* k  = (const float*)d_in[1];
    const float* v  = (const float*)d_in[2];
    const float* supp_valid = (const float*)d_in[3];
    const int*   supp_mask  = (const int*)d_in[4];
    const float* Wq = (const float*)d_in[5];
    const float* Wk = (const float*)d_in[6];
    const float* Wv = (const float*)d_in[7];
    const float* Wp = (const float*)d_in[8];
    float* out = (float*)d_out;

    char* p = (char*)d_ws;
    _Float16* qhi = (_Float16*)p;      p += 4194304;   // [bh][n][d] f16 splits
    _Float16* qlo = (_Float16*)p;      p += 4194304;
    _Float16* khi = (_Float16*)p;      p += 4194304;
    _Float16* klo = (_Float16*)p;      p += 4194304;
    _Float16* vT  = (_Float16*)p;      p += 4194304;   // [bh] chunk-tiled (k')
    float* xp     = (float*)p;         p += 16777216;  // [2][4096][512] f32
    _Float16* wH  = (_Float16*)p;      p += 2097152;   // [4][512*512]
    _Float16* wL  = (_Float16*)p;      p += 2097152;
    unsigned long long* q2kP = (unsigned long long*)p; p += 262144;
    unsigned long long* k2qP = (unsigned long long*)p; p += 262144;
    float* lp = (float*)p;             p += 262144;    // [2][16][2048]
    float* validNeg = (float*)p;       p += 131072;

    hipMemsetAsync(q2kP, 0, 524288, stream);           // rowP + colP zero init

    dim3 bG(256);
    wsplit4<<<dim3(256, 4), bG, 0, stream>>>(Wq, Wk, Wv, Wp, wH, wL);
    proj_gemm<<<dim3(32, 8, 3), bG, 0, stream>>>(q, k, v, wH, wL,
                                                 qhi, qlo, khi, klo, vT);

    argmax_mfma<<<1024, bG, 0, stream>>>(qhi, qlo, khi, klo, q2kP, k2qP);

    resolve<<<128, bG, 0, stream>>>(q2kP, k2qP, supp_mask, supp_valid, validNeg);

    attn_pv<<<1024, bG, 0, stream>>>(qhi, khi, vT, validNeg, xp, lp);

    out_gemm<<<dim3(32, 8), bG, 0, stream>>>(xp, lp,
                                             wH + 3 * 262144, wL + 3 * 262144, out);
}